// Round 7
// baseline (200.293 us; speedup 1.0000x reference)
//
#include <hip/hip_runtime.h>

#define NTRAIN 32768
#define NBDY   4096
#define PHYS_BLOCKS (NTRAIN / 32)   // 1024 blocks, 32 pts each
#define BDY_BLOCKS  256             // 64 pts/block, 64 blocks per batch

typedef _Float16 f16x8 __attribute__((ext_vector_type(8)));
typedef __fp16   fp16x2 __attribute__((ext_vector_type(2)));
typedef float    f32x4 __attribute__((ext_vector_type(4)));

union FragU { uint4 q; f16x8 b; _Float16 e[8]; };
union F4  { float4 v; float f[4]; };
union H2  { fp16x2 h; _Float16 e[2]; unsigned int u; };

__device__ __forceinline__ float fast_tanh(float z) {
    float e = __expf(2.0f * z);
    return 1.0f - 2.0f * __builtin_amdgcn_rcpf(e + 1.0f);
}

__device__ __forceinline__ unsigned int pk2(float a, float b) {
    H2 r; r.h = __builtin_amdgcn_cvt_pkrtz(a, b);
    return r.u;
}

// XOR bank swizzle for the stride-128 (ushort) A-tile: flips ush bits 3..5
// with row&7. All accesses are uint2 (4-ush aligned) or uint4 (8-ush
// aligned); XOR of >=8-ush multiples never straddles an access.
__device__ __forceinline__ int swz(int row, int col) {
    return (row * 128 + col) ^ ((row & 7) << 3);
}

// ---------------------------------------------------------------------------
// Pack weights into MFMA A-fragment order (fp16 hi+lo).  (unchanged)
// W1..W3: hi at wsU + l*32768, lo at +16384 (lo unused by fused hidden layers).
// V1-hi at wsU+98304. W4 padded 128x16: hi at wsU+102400, lo +2048.
// Block 24 zeroes out[0].
// ---------------------------------------------------------------------------
__global__ __launch_bounds__(256) void pack_w_kernel(
    const float* __restrict__ W1, const float* __restrict__ W2,
    const float* __restrict__ W3, const float* __restrict__ V1,
    const float* __restrict__ W4,
    unsigned short* __restrict__ wsU, float* __restrict__ out)
{
    int b = blockIdx.x;
    if (b < 24) {
        int mat = b >> 3, rb = b & 7;          // 16 rows per block
        const float* W = (mat == 0) ? W1 : (mat == 1) ? W2 : W3;
        unsigned int* hiU = (unsigned int*)(wsU + mat * 32768);
        unsigned int* loU = hiU + 8192;
        int n   = threadIdx.x & 127;
        int pr0 = threadIdx.x >> 7;
        #pragma unroll
        for (int it = 0; it < 4; it++) {
            int pr = pr0 + 2 * it;
            int k  = rb * 16 + pr * 2;
            float v0 = W[k * 128 + n];
            float v1 = W[(k + 1) * 128 + n];
            H2 hh, ll;
            hh.e[0] = (_Float16)v0;
            hh.e[1] = (_Float16)v1;
            ll.e[0] = (_Float16)(v0 - (float)hh.e[0]);
            ll.e[1] = (_Float16)(v1 - (float)hh.e[1]);
            int base = ((n >> 4) * 4 + (k >> 5)) * 64 + ((k >> 3) & 3) * 16 + (n & 15);
            int uoff = base * 4 + ((k & 7) >> 1);
            hiU[uoff] = hh.u;
            loU[uoff] = ll.u;
        }
    } else if (b == 24) {
        unsigned int* hiU = (unsigned int*)(wsU + 98304);
        int n   = threadIdx.x & 63;
        int pr0 = threadIdx.x >> 6;
        #pragma unroll
        for (int it = 0; it < 8; it++) {
            int pr = pr0 + 4 * it;
            int k  = pr * 2;
            float v0 = V1[k * 64 + n];
            float v1 = V1[(k + 1) * 64 + n];
            H2 hh;
            hh.e[0] = (_Float16)v0;
            hh.e[1] = (_Float16)v1;
            int base = ((n >> 4) * 2 + (k >> 5)) * 64 + ((k >> 3) & 3) * 16 + (n & 15);
            hiU[base * 4 + ((k & 7) >> 1)] = hh.u;
        }
        if (threadIdx.x == 0) out[0] = 0.f;
    } else {
        _Float16* hi = (_Float16*)(wsU + 102400);
        _Float16* lo = hi + 2048;
        int u4 = threadIdx.x;
        int lane = u4 & 63, ks = u4 >> 6;
        int m  = lane & 15;
        int kb = ks * 32 + ((lane >> 4) << 3);
        FragU fh, fl;
        #pragma unroll
        for (int j = 0; j < 8; j++) {
            float v = (m < 4) ? W4[(kb + j) * 4 + m] : 0.f;
            _Float16 h = (_Float16)v;
            fh.e[j] = h;
            fl.e[j] = (_Float16)(v - (float)h);
        }
        *(uint4*)(hi + u4 * 8) = fh.q;
        *(uint4*)(lo + u4 * 8) = fl.q;
    }
}

// ---------------------------------------------------------------------------
// Fused kernel, r24 = r18 with LDS cut to EXACTLY 32,768 B -> 5 blocks/CU
// (20 waves/CU, +25% TLP).  Changes vs r18:
//  (1) A-tile stride 136 -> 128 ushorts + XOR bank swizzle (swz) everywhere.
//  (2) OUTF/MUPART eliminated: waves 0,1 own point-group 0,1 end-to-end --
//      full mu in-register (4 V1-tiles each), L4 = all 4 stream tiles of own
//      group (lane nn,q=0 then holds V/DX/DY/LAP of its point), residual
//      lane-local. No post-L4 barrier. Boundary: L4 tile wv = own points ->
//      loss lane-local, no OUTB.
//  (3) BIASF/BIASB eliminated: biases read from L1 in the epilogues.
// Barriers 9 -> 7. launch_bounds(256,5) = 96-VGPR budget.
// ---------------------------------------------------------------------------
__global__ __launch_bounds__(256, 5) void fused_kernel(
    const float* __restrict__ xt,
    const float* __restrict__ x_inlet, const float* __restrict__ U_inlet,
    const float* __restrict__ x_base,  const float* __restrict__ x_top,
    const float* __restrict__ x_slip,
    const float* __restrict__ W0, const float* __restrict__ b0,
    const float* __restrict__ W1, const float* __restrict__ b1,
    const float* __restrict__ W2, const float* __restrict__ b2,
    const float* __restrict__ W3, const float* __restrict__ b3,
    const float* __restrict__ W4, const float* __restrict__ b4,
    const float* __restrict__ V0, const float* __restrict__ c0,
    const float* __restrict__ V1, const float* __restrict__ c1,
    const float* __restrict__ V2, const float* __restrict__ c2,
    const unsigned short* __restrict__ wsU,
    float* __restrict__ out)
{
    __shared__ unsigned short AhU[16384];   // 32,768 B: 128 rows x 128 (swz)
    const int t = threadIdx.x;
    const int wv   = t >> 6;
    const int lane = t & 63;
    const int nn   = lane & 15;
    const int q    = lane >> 4;

    if (blockIdx.x < PHYS_BLOCKS) {
        // =================== PHYSICS PATH (32 pts) ===================
        const int blk = blockIdx.x;

        // ---- mu net: waves 0,1 compute FULL mu for their point-group ----
        float mu = 0.f;
        if (wv < 2) {
            const float2 xyn = *(const float2*)(xt + (blk * 32 + wv * 16 + nn) * 2);
            FragU mb[2];
            #pragma unroll
            for (int ks = 0; ks < 2; ks++) {
                int u0 = ks * 32 + q * 8;
                F4 va0, va1, vb0, vb1, cc0, cc1;
                va0.v = *(const float4*)(V0 + u0);
                va1.v = *(const float4*)(V0 + u0 + 4);
                vb0.v = *(const float4*)(V0 + 64 + u0);
                vb1.v = *(const float4*)(V0 + 64 + u0 + 4);
                cc0.v = *(const float4*)(c0 + u0);
                cc1.v = *(const float4*)(c0 + u0 + 4);
                #pragma unroll
                for (int i = 0; i < 4; i++) {
                    mb[ks].e[i]     = (_Float16)fast_tanh(
                        xyn.x * va0.f[i] + xyn.y * vb0.f[i] + cc0.f[i]);
                    mb[ks].e[4 + i] = (_Float16)fast_tanh(
                        xyn.x * va1.f[i] + xyn.y * vb1.f[i] + cc1.f[i]);
                }
            }
            float partial = 0.f;
            #pragma unroll
            for (int tu = 0; tu < 4; tu++) {
                f32x4 macc = {0.f, 0.f, 0.f, 0.f};
                #pragma unroll
                for (int ks = 0; ks < 2; ks++) {
                    FragU vh;
                    vh.q = *(const uint4*)(wsU + 98304 +
                           (((tu * 2 + ks) * 64 + lane) << 3));
                    macc = __builtin_amdgcn_mfma_f32_16x16x32_f16(vh.b, mb[ks].b, macc, 0, 0, 0);
                }
                int u2 = tu * 16 + q * 4;
                F4 cv, w2;
                cv.v = *(const float4*)(c1 + u2);
                w2.v = *(const float4*)(V2 + u2);
                #pragma unroll
                for (int r = 0; r < 4; r++)
                    partial += fast_tanh(macc[r] + cv.f[r]) * w2.f[r];
            }
            partial += __shfl_xor(partial, 16);
            partial += __shfl_xor(partial, 32);
            float s = partial + c2[0];
            mu = 0.01f * s * s;
        }
        {   // main layer 0: 2 -> 128, 4 streams, 2 point-halves per thread
            const int pl = t >> 4, c = t & 15;
            #pragma unroll
            for (int h2 = 0; h2 < 2; h2++) {
                const int p = h2 * 16 + pl;
                const float2 xy = *(const float2*)(xt + (blk * 32 + p) * 2);
                const float x = xy.x, y = xy.y;
                float vals[4][8];
                #pragma unroll
                for (int j = 0; j < 8; j++) {
                    int u = c * 8 + j;
                    float w0 = W0[u], w1 = W0[128 + u];
                    float zv = x * w0 + y * w1 + b0[u];
                    float tt = fast_tanh(zv);
                    float s2 = 1.f - tt * tt;
                    float m2 = -2.f * tt * s2;
                    vals[0][j] = tt;
                    vals[1][j] = s2 * w0;
                    vals[2][j] = s2 * w1;
                    vals[3][j] = m2 * (w0 * w0 + w1 * w1);  // z_lap = 0 at layer 0
                }
                #pragma unroll
                for (int s = 0; s < 4; s++) {
                    uint4 d = make_uint4(pk2(vals[s][0], vals[s][1]),
                                         pk2(vals[s][2], vals[s][3]),
                                         pk2(vals[s][4], vals[s][5]),
                                         pk2(vals[s][6], vals[s][7]));
                    *(uint4*)(AhU + swz((h2 * 4 + s) * 16 + pl, c * 8)) = d;
                }
            }
        }
        __syncthreads();

        // ------- hidden layers 1..3 via MFMA (8 row-tiles, W-hi 1-pass) ----
        #pragma unroll 1
        for (int l = 0; l < 3; l++) {
            const unsigned short* WpL = wsU + l * 32768;
            const float* bl = (l == 0) ? b1 : (l == 1) ? b2 : b3;
            f32x4 acc[2][8];
            #pragma unroll
            for (int i = 0; i < 2; i++)
                #pragma unroll
                for (int s = 0; s < 8; s++) {
                    acc[i][s][0] = 0.f; acc[i][s][1] = 0.f;
                    acc[i][s][2] = 0.f; acc[i][s][3] = 0.f;
                }
            #pragma unroll
            for (int ks = 0; ks < 4; ks++) {
                FragU wh[2];
                #pragma unroll
                for (int i = 0; i < 2; i++)
                    wh[i].q = *(const uint4*)(WpL + ((((2 * wv + i) * 4 + ks) * 64 + lane) << 3));
                #pragma unroll
                for (int s = 0; s < 8; s++) {
                    FragU bh;
                    bh.q = *(const uint4*)(AhU + swz(s * 16 + nn, ks * 32 + q * 8));
                    acc[0][s] = __builtin_amdgcn_mfma_f32_16x16x32_f16(
                        wh[0].b, bh.b, acc[0][s], 0, 0, 0);
                    acc[1][s] = __builtin_amdgcn_mfma_f32_16x16x32_f16(
                        wh[1].b, bh.b, acc[1][s], 0, 0, 0);
                }
            }
            __syncthreads();   // all A reads done before overwrite
            #pragma unroll
            for (int i = 0; i < 2; i++) {
                const int ubase = (2 * wv + i) * 16 + q * 4;
                F4 bv; bv.v = *(const float4*)(bl + ubase);
                #pragma unroll
                for (int g = 0; g < 2; g++) {
                    float vals[4][4];
                    #pragma unroll
                    for (int r = 0; r < 4; r++) {
                        float z  = acc[i][g * 4 + 0][r] + bv.f[r];
                        float zx = acc[i][g * 4 + 1][r];
                        float zy = acc[i][g * 4 + 2][r];
                        float zl = acc[i][g * 4 + 3][r];
                        float tt = fast_tanh(z);
                        float s2 = 1.f - tt * tt;
                        float m2 = -2.f * tt * s2;
                        vals[0][r] = tt;
                        vals[1][r] = s2 * zx;
                        vals[2][r] = s2 * zy;
                        vals[3][r] = s2 * zl + m2 * (zx * zx + zy * zy);
                    }
                    #pragma unroll
                    for (int s = 0; s < 4; s++) {
                        uint2 d = make_uint2(pk2(vals[s][0], vals[s][1]),
                                             pk2(vals[s][2], vals[s][3]));
                        *(uint2*)(AhU + swz((g * 4 + s) * 16 + nn, ubase)) = d;
                    }
                }
            }
            __syncthreads();
        }

        // ---- layer 4 + residual: waves 0,1 own their point-group fully ----
        if (wv < 2) {
            const unsigned short* W4p = wsU + 102400;
            f32x4 a4[4];
            #pragma unroll
            for (int s = 0; s < 4; s++) {
                a4[s][0] = 0.f; a4[s][1] = 0.f; a4[s][2] = 0.f; a4[s][3] = 0.f;
            }
            #pragma unroll
            for (int ks = 0; ks < 4; ks++) {
                FragU wh, wl;
                const unsigned short* base = W4p + ((ks * 64 + lane) << 3);
                wh.q = *(const uint4*)base;
                wl.q = *(const uint4*)(base + 2048);
                #pragma unroll
                for (int s = 0; s < 4; s++) {
                    FragU bh;
                    bh.q = *(const uint4*)(AhU + swz((wv * 4 + s) * 16 + nn, ks * 32 + q * 8));
                    a4[s] = __builtin_amdgcn_mfma_f32_16x16x32_f16(wh.b, bh.b, a4[s], 0, 0, 0);
                    a4[s] = __builtin_amdgcn_mfma_f32_16x16x32_f16(wl.b, bh.b, a4[s], 0, 0, 0);
                }
            }
            float contrib = 0.f;
            if (q == 0) {
                float r  = a4[0][0] + b4[0], P = a4[0][1] + b4[1];
                float u  = a4[0][2] + b4[2], v = a4[0][3] + b4[3];
                float rx = a4[1][0], Px = a4[1][1], ux = a4[1][2], vx = a4[1][3];
                float ry = a4[2][0], Py = a4[2][1], uy = a4[2][2], vy = a4[2][3];
                float rl = a4[3][0], Pl = a4[3][1], ul = a4[3][2], vl = a4[3][3];
                const float GI = 2.5f;  // 1/(gamma-1)

                float q2 = u * u + v * v;
                float E  = P * GI + 0.5f * r * q2;
                float Ex = Px * GI + 0.5f * rx * q2 + r * (u * ux + v * vx);
                float Ey = Py * GI + 0.5f * ry * q2 + r * (u * uy + v * vy);
                float EpP = E + P;

                float f1x = rx * u + r * ux;
                float f2x = rx * u * u + 2.f * r * u * ux + Px;
                float f3x = rx * u * v + r * ux * v + r * u * vx;
                float f4x = ux * EpP + u * (Ex + Px);

                float g1y = ry * v + r * vy;
                float g2y = ry * u * v + r * uy * v + r * u * vy;
                float g3y = ry * v * v + 2.f * r * v * vy + Py;
                float g4y = vy * EpP + v * (Ey + Py);

                float qx  = 2.f * (u * ux + v * vx);
                float qy  = 2.f * (u * uy + v * vy);
                float ql  = 2.f * (ux * ux + uy * uy + vx * vx + vy * vy)
                          + 2.f * (u * ul + v * vl);

                float U1s = rl;
                float U2s = rl * u + 2.f * (rx * ux + ry * uy) + r * ul;
                float U3s = rl * v + 2.f * (rx * vx + ry * vy) + r * vl;
                float U4s = Pl * GI
                          + 0.5f * (rl * q2 + 2.f * (rx * qx + ry * qy) + r * ql);

                float r1 = f1x + g1y - mu * U1s;
                float r2 = f2x + g2y - mu * U2s;
                float r3 = f3x + g3y - mu * U3s;
                float r4 = f4x + g4y - mu * U4s;

                contrib = (r1 * r1 + r2 * r2 + r3 * r3 + r4 * r4 + 0.1f * mu * mu)
                          * (1.0f / (float)NTRAIN);
            }
            contrib += __shfl_down(contrib, 32);
            contrib += __shfl_down(contrib, 16);
            contrib += __shfl_down(contrib, 8);
            contrib += __shfl_down(contrib, 4);
            contrib += __shfl_down(contrib, 2);
            contrib += __shfl_down(contrib, 1);
            if (lane == 0) atomicAdd(out, contrib);
        }
    } else {
        // =================== BOUNDARY PATH (MFMA, 64 pts/block) ============
        const int bb    = blockIdx.x - PHYS_BLOCKS;
        const int batch = bb >> 6;  // 0..3 (64 blocks each)
        const int lb    = bb & 63;
        const float* xs = (batch == 0) ? x_inlet
                        : (batch == 1) ? x_base
                        : (batch == 2) ? x_top : x_slip;
        const int base_pt = lb * 64;

        // ---- layer 0: 2 -> 128 (4 threads/pt, 32 units each) ----
        {
            int p2 = t & 63, ug = t >> 6;
            float2 xy = *(const float2*)(xs + (base_pt + p2) * 2);
            float x = xy.x, y = xy.y;
            #pragma unroll
            for (int g = 0; g < 8; g++) {
                int u0 = ug * 32 + g * 4;
                F4 wa, wb, bbv;
                wa.v  = *(const float4*)(W0 + u0);
                wb.v  = *(const float4*)(W0 + 128 + u0);
                bbv.v = *(const float4*)(b0 + u0);
                float t0 = fast_tanh(x * wa.f[0] + y * wb.f[0] + bbv.f[0]);
                float t1 = fast_tanh(x * wa.f[1] + y * wb.f[1] + bbv.f[1]);
                float t2 = fast_tanh(x * wa.f[2] + y * wb.f[2] + bbv.f[2]);
                float t3 = fast_tanh(x * wa.f[3] + y * wb.f[3] + bbv.f[3]);
                uint2 d = make_uint2(pk2(t0, t1), pk2(t2, t3));
                *(uint2*)(AhU + swz(p2, u0)) = d;
            }
        }
        __syncthreads();

        // ---- hidden layers 1..3 via MFMA (W hi only, 4 point-tiles) ----
        #pragma unroll 1
        for (int l = 0; l < 3; l++) {
            const unsigned short* WpL = wsU + l * 32768;
            const float* bl = (l == 0) ? b1 : (l == 1) ? b2 : b3;
            f32x4 acc[2][4];
            #pragma unroll
            for (int i = 0; i < 2; i++)
                #pragma unroll
                for (int n = 0; n < 4; n++) {
                    acc[i][n][0] = 0.f; acc[i][n][1] = 0.f;
                    acc[i][n][2] = 0.f; acc[i][n][3] = 0.f;
                }
            #pragma unroll
            for (int ks = 0; ks < 4; ks++) {
                FragU bh[4];
                #pragma unroll
                for (int n = 0; n < 4; n++)
                    bh[n].q = *(const uint4*)(AhU + swz(n * 16 + nn, ks * 32 + q * 8));
                FragU wh[2];
                #pragma unroll
                for (int i = 0; i < 2; i++)
                    wh[i].q = *(const uint4*)(WpL + ((((2 * wv + i) * 4 + ks) * 64 + lane) << 3));
                #pragma unroll
                for (int i = 0; i < 2; i++)
                    #pragma unroll
                    for (int n = 0; n < 4; n++)
                        acc[i][n] = __builtin_amdgcn_mfma_f32_16x16x32_f16(
                            wh[i].b, bh[n].b, acc[i][n], 0, 0, 0);
            }
            __syncthreads();
            #pragma unroll
            for (int i = 0; i < 2; i++) {
                int ubase = (2 * wv + i) * 16 + q * 4;
                F4 bv; bv.v = *(const float4*)(bl + ubase);
                #pragma unroll
                for (int n = 0; n < 4; n++) {
                    float t0 = fast_tanh(acc[i][n][0] + bv.f[0]);
                    float t1 = fast_tanh(acc[i][n][1] + bv.f[1]);
                    float t2 = fast_tanh(acc[i][n][2] + bv.f[2]);
                    float t3 = fast_tanh(acc[i][n][3] + bv.f[3]);
                    uint2 d = make_uint2(pk2(t0, t1), pk2(t2, t3));
                    *(uint2*)(AhU + swz(n * 16 + nn, ubase)) = d;
                }
            }
            __syncthreads();
        }

        // ---- layer 4 (padded W4, hi+lo), tile wv = own points; loss local --
        {
            const unsigned short* W4p = wsU + 102400;
            f32x4 a4 = {0.f, 0.f, 0.f, 0.f};
            #pragma unroll
            for (int ks = 0; ks < 4; ks++) {
                FragU bh, wh, wl;
                bh.q = *(const uint4*)(AhU + swz(wv * 16 + nn, ks * 32 + q * 8));
                const unsigned short* base = W4p + ((ks * 64 + lane) << 3);
                wh.q = *(const uint4*)base;
                wl.q = *(const uint4*)(base + 2048);
                a4 = __builtin_amdgcn_mfma_f32_16x16x32_f16(wh.b, bh.b, a4, 0, 0, 0);
                a4 = __builtin_amdgcn_mfma_f32_16x16x32_f16(wl.b, bh.b, a4, 0, 0, 0);
            }
            float contrib = 0.f;
            if (q == 0) {
                float o0 = a4[0] + b4[0], o1 = a4[1] + b4[1];
                float o2 = a4[2] + b4[2], o3 = a4[3] + b4[3];
                float l;
                if (batch == 0) {
                    float4 Ui = *(const float4*)(U_inlet + (base_pt + wv * 16 + nn) * 4);
                    float d0 = o0 - Ui.x, d1 = o1 - Ui.y, d2 = o2 - Ui.z, d3 = o3 - Ui.w;
                    l = d0 * d0 + d1 * d1 + d2 * d2 + d3 * d3;
                } else if (batch == 3) {
                    const float sa = -0.17364817766693033f;  // sin(-pi/18)
                    const float ca =  0.9848077530122080f;   // cos(-pi/18)
                    float d = -o2 * sa + o3 * ca;
                    l = d * d;
                } else {
                    l = o3 * o3;
                }
                contrib = 10.0f * l * (1.0f / (float)NBDY);
            }
            contrib += __shfl_down(contrib, 32);
            contrib += __shfl_down(contrib, 16);
            contrib += __shfl_down(contrib, 8);
            contrib += __shfl_down(contrib, 4);
            contrib += __shfl_down(contrib, 2);
            contrib += __shfl_down(contrib, 1);
            if (lane == 0) atomicAdd(out, contrib);
        }
    }
}

extern "C" void kernel_launch(void* const* d_in, const int* in_sizes, int n_in,
                              void* d_out, int out_size, void* d_ws, size_t ws_size,
                              hipStream_t stream) {
    const float* xt      = (const float*)d_in[0];
    const float* x_inlet = (const float*)d_in[1];
    const float* U_inlet = (const float*)d_in[2];
    const float* x_base  = (const float*)d_in[3];
    const float* x_top   = (const float*)d_in[4];
    const float* x_slip  = (const float*)d_in[5];
    const float* W0 = (const float*)d_in[6];
    const float* b0 = (const float*)d_in[7];
    const float* W1 = (const float*)d_in[8];
    const float* b1 = (const float*)d_in[9];
    const float* W2 = (const float*)d_in[10];
    const float* b2 = (const float*)d_in[11];
    const float* W3 = (const float*)d_in[12];
    const float* b3 = (const float*)d_in[13];
    const float* W4 = (const float*)d_in[14];
    const float* b4 = (const float*)d_in[15];
    const float* V0 = (const float*)d_in[16];
    const float* c0 = (const float*)d_in[17];
    const float* V1 = (const float*)d_in[18];
    const float* c1 = (const float*)d_in[19];
    const float* V2 = (const float*)d_in[20];
    const float* c2 = (const float*)d_in[21];
    float* out = (float*)d_out;
    unsigned short* wsU = (unsigned short*)d_ws;

    pack_w_kernel<<<26, 256, 0, stream>>>(W1, W2, W3, V1, W4, wsU, out);

    fused_kernel<<<PHYS_BLOCKS + BDY_BLOCKS, 256, 0, stream>>>(
        xt, x_inlet, U_inlet, x_base, x_top, x_slip,
        W0, b0, W1, b1, W2, b2, W3, b3, W4, b4,
        V0, c0, V1, c1, V2, c2, wsU, out);
}

// Round 8
// 187.777 us; speedup vs baseline: 1.0667x; 1.0667x over previous
//
#include <hip/hip_runtime.h>

#define NTRAIN 32768
#define NBDY   4096
#define PHYS_BLOCKS (NTRAIN / 32)   // 1024 blocks, 32 pts each
#define BDY_BLOCKS  256             // 64 pts/block, 64 blocks per batch

typedef _Float16 f16x8 __attribute__((ext_vector_type(8)));
typedef __fp16   fp16x2 __attribute__((ext_vector_type(2)));
typedef float    f32x4 __attribute__((ext_vector_type(4)));

union FragU { uint4 q; f16x8 b; _Float16 e[8]; };
union F4  { float4 v; float f[4]; };
union H2  { fp16x2 h; _Float16 e[2]; unsigned int u; };

__device__ __forceinline__ float fast_tanh(float z) {
    float e = __expf(2.0f * z);
    return 1.0f - 2.0f * __builtin_amdgcn_rcpf(e + 1.0f);
}

__device__ __forceinline__ unsigned int pk2(float a, float b) {
    H2 r; r.h = __builtin_amdgcn_cvt_pkrtz(a, b);
    return r.u;
}

// XOR bank swizzle for the stride-128 (ushort) A-tile: flips ush bits 3..5
// with row&7. All accesses are uint2 (4-ush aligned) or uint4 (8-ush
// aligned); XOR of >=8-ush multiples never straddles an access.
__device__ __forceinline__ int swz(int row, int col) {
    return (row * 128 + col) ^ ((row & 7) << 3);
}

// ---------------------------------------------------------------------------
// Pack weights into MFMA A-fragment order (fp16 hi+lo).  (unchanged)
// W1..W3: hi at wsU + l*32768, lo at +16384 (lo unused by fused hidden layers).
// V1-hi at wsU+98304. W4 padded 128x16: hi at wsU+102400, lo +2048.
// Block 24 zeroes out[0].
// ---------------------------------------------------------------------------
__global__ __launch_bounds__(256) void pack_w_kernel(
    const float* __restrict__ W1, const float* __restrict__ W2,
    const float* __restrict__ W3, const float* __restrict__ V1,
    const float* __restrict__ W4,
    unsigned short* __restrict__ wsU, float* __restrict__ out)
{
    int b = blockIdx.x;
    if (b < 24) {
        int mat = b >> 3, rb = b & 7;          // 16 rows per block
        const float* W = (mat == 0) ? W1 : (mat == 1) ? W2 : W3;
        unsigned int* hiU = (unsigned int*)(wsU + mat * 32768);
        unsigned int* loU = hiU + 8192;
        int n   = threadIdx.x & 127;
        int pr0 = threadIdx.x >> 7;
        #pragma unroll
        for (int it = 0; it < 4; it++) {
            int pr = pr0 + 2 * it;
            int k  = rb * 16 + pr * 2;
            float v0 = W[k * 128 + n];
            float v1 = W[(k + 1) * 128 + n];
            H2 hh, ll;
            hh.e[0] = (_Float16)v0;
            hh.e[1] = (_Float16)v1;
            ll.e[0] = (_Float16)(v0 - (float)hh.e[0]);
            ll.e[1] = (_Float16)(v1 - (float)hh.e[1]);
            int base = ((n >> 4) * 4 + (k >> 5)) * 64 + ((k >> 3) & 3) * 16 + (n & 15);
            int uoff = base * 4 + ((k & 7) >> 1);
            hiU[uoff] = hh.u;
            loU[uoff] = ll.u;
        }
    } else if (b == 24) {
        unsigned int* hiU = (unsigned int*)(wsU + 98304);
        int n   = threadIdx.x & 63;
        int pr0 = threadIdx.x >> 6;
        #pragma unroll
        for (int it = 0; it < 8; it++) {
            int pr = pr0 + 4 * it;
            int k  = pr * 2;
            float v0 = V1[k * 64 + n];
            float v1 = V1[(k + 1) * 64 + n];
            H2 hh;
            hh.e[0] = (_Float16)v0;
            hh.e[1] = (_Float16)v1;
            int base = ((n >> 4) * 2 + (k >> 5)) * 64 + ((k >> 3) & 3) * 16 + (n & 15);
            hiU[base * 4 + ((k & 7) >> 1)] = hh.u;
        }
        if (threadIdx.x == 0) out[0] = 0.f;
    } else {
        _Float16* hi = (_Float16*)(wsU + 102400);
        _Float16* lo = hi + 2048;
        int u4 = threadIdx.x;
        int lane = u4 & 63, ks = u4 >> 6;
        int m  = lane & 15;
        int kb = ks * 32 + ((lane >> 4) << 3);
        FragU fh, fl;
        #pragma unroll
        for (int j = 0; j < 8; j++) {
            float v = (m < 4) ? W4[(kb + j) * 4 + m] : 0.f;
            _Float16 h = (_Float16)v;
            fh.e[j] = h;
            fl.e[j] = (_Float16)(v - (float)h);
        }
        *(uint4*)(hi + u4 * 8) = fh.q;
        *(uint4*)(lo + u4 * 8) = fl.q;
    }
}

// ---------------------------------------------------------------------------
// Fused kernel, r25 = r24 structure with launch_bounds(256,4) (128-VGPR
// budget; r24's (256,5) pin caused catastrophic scratch spill at 48 VGPR).
// Structure (verified correct on HW in r24): 32,768 B LDS exactly ->
// 5 blocks/CU when VGPR <= ~102:
//  (1) A-tile stride 128 ushorts + XOR bank swizzle (swz).
//  (2) No OUTF/MUPART: waves 0,1 own their point-group end-to-end (full mu
//      in-register, all 4 L4 stream-tiles, lane-local residual).
//  (3) No BIASF: biases from L1 in epilogues.
// ---------------------------------------------------------------------------
__global__ __launch_bounds__(256, 4) void fused_kernel(
    const float* __restrict__ xt,
    const float* __restrict__ x_inlet, const float* __restrict__ U_inlet,
    const float* __restrict__ x_base,  const float* __restrict__ x_top,
    const float* __restrict__ x_slip,
    const float* __restrict__ W0, const float* __restrict__ b0,
    const float* __restrict__ W1, const float* __restrict__ b1,
    const float* __restrict__ W2, const float* __restrict__ b2,
    const float* __restrict__ W3, const float* __restrict__ b3,
    const float* __restrict__ W4, const float* __restrict__ b4,
    const float* __restrict__ V0, const float* __restrict__ c0,
    const float* __restrict__ V1, const float* __restrict__ c1,
    const float* __restrict__ V2, const float* __restrict__ c2,
    const unsigned short* __restrict__ wsU,
    float* __restrict__ out)
{
    __shared__ unsigned short AhU[16384];   // 32,768 B: 128 rows x 128 (swz)
    const int t = threadIdx.x;
    const int wv   = t >> 6;
    const int lane = t & 63;
    const int nn   = lane & 15;
    const int q    = lane >> 4;

    if (blockIdx.x < PHYS_BLOCKS) {
        // =================== PHYSICS PATH (32 pts) ===================
        const int blk = blockIdx.x;

        // ---- mu net: waves 0,1 compute FULL mu for their point-group ----
        float mu = 0.f;
        if (wv < 2) {
            const float2 xyn = *(const float2*)(xt + (blk * 32 + wv * 16 + nn) * 2);
            FragU mb[2];
            #pragma unroll
            for (int ks = 0; ks < 2; ks++) {
                int u0 = ks * 32 + q * 8;
                F4 va0, va1, vb0, vb1, cc0, cc1;
                va0.v = *(const float4*)(V0 + u0);
                va1.v = *(const float4*)(V0 + u0 + 4);
                vb0.v = *(const float4*)(V0 + 64 + u0);
                vb1.v = *(const float4*)(V0 + 64 + u0 + 4);
                cc0.v = *(const float4*)(c0 + u0);
                cc1.v = *(const float4*)(c0 + u0 + 4);
                #pragma unroll
                for (int i = 0; i < 4; i++) {
                    mb[ks].e[i]     = (_Float16)fast_tanh(
                        xyn.x * va0.f[i] + xyn.y * vb0.f[i] + cc0.f[i]);
                    mb[ks].e[4 + i] = (_Float16)fast_tanh(
                        xyn.x * va1.f[i] + xyn.y * vb1.f[i] + cc1.f[i]);
                }
            }
            float partial = 0.f;
            #pragma unroll
            for (int tu = 0; tu < 4; tu++) {
                f32x4 macc = {0.f, 0.f, 0.f, 0.f};
                #pragma unroll
                for (int ks = 0; ks < 2; ks++) {
                    FragU vh;
                    vh.q = *(const uint4*)(wsU + 98304 +
                           (((tu * 2 + ks) * 64 + lane) << 3));
                    macc = __builtin_amdgcn_mfma_f32_16x16x32_f16(vh.b, mb[ks].b, macc, 0, 0, 0);
                }
                int u2 = tu * 16 + q * 4;
                F4 cv, w2;
                cv.v = *(const float4*)(c1 + u2);
                w2.v = *(const float4*)(V2 + u2);
                #pragma unroll
                for (int r = 0; r < 4; r++)
                    partial += fast_tanh(macc[r] + cv.f[r]) * w2.f[r];
            }
            partial += __shfl_xor(partial, 16);
            partial += __shfl_xor(partial, 32);
            float s = partial + c2[0];
            mu = 0.01f * s * s;
        }
        {   // main layer 0: 2 -> 128, 4 streams, 2 point-halves per thread
            const int pl = t >> 4, c = t & 15;
            #pragma unroll
            for (int h2 = 0; h2 < 2; h2++) {
                const int p = h2 * 16 + pl;
                const float2 xy = *(const float2*)(xt + (blk * 32 + p) * 2);
                const float x = xy.x, y = xy.y;
                float vals[4][8];
                #pragma unroll
                for (int j = 0; j < 8; j++) {
                    int u = c * 8 + j;
                    float w0 = W0[u], w1 = W0[128 + u];
                    float zv = x * w0 + y * w1 + b0[u];
                    float tt = fast_tanh(zv);
                    float s2 = 1.f - tt * tt;
                    float m2 = -2.f * tt * s2;
                    vals[0][j] = tt;
                    vals[1][j] = s2 * w0;
                    vals[2][j] = s2 * w1;
                    vals[3][j] = m2 * (w0 * w0 + w1 * w1);  // z_lap = 0 at layer 0
                }
                #pragma unroll
                for (int s = 0; s < 4; s++) {
                    uint4 d = make_uint4(pk2(vals[s][0], vals[s][1]),
                                         pk2(vals[s][2], vals[s][3]),
                                         pk2(vals[s][4], vals[s][5]),
                                         pk2(vals[s][6], vals[s][7]));
                    *(uint4*)(AhU + swz((h2 * 4 + s) * 16 + pl, c * 8)) = d;
                }
            }
        }
        __syncthreads();

        // ------- hidden layers 1..3 via MFMA (8 row-tiles, W-hi 1-pass) ----
        #pragma unroll 1
        for (int l = 0; l < 3; l++) {
            const unsigned short* WpL = wsU + l * 32768;
            const float* bl = (l == 0) ? b1 : (l == 1) ? b2 : b3;
            f32x4 acc[2][8];
            #pragma unroll
            for (int i = 0; i < 2; i++)
                #pragma unroll
                for (int s = 0; s < 8; s++) {
                    acc[i][s][0] = 0.f; acc[i][s][1] = 0.f;
                    acc[i][s][2] = 0.f; acc[i][s][3] = 0.f;
                }
            #pragma unroll
            for (int ks = 0; ks < 4; ks++) {
                FragU wh[2];
                #pragma unroll
                for (int i = 0; i < 2; i++)
                    wh[i].q = *(const uint4*)(WpL + ((((2 * wv + i) * 4 + ks) * 64 + lane) << 3));
                #pragma unroll
                for (int s = 0; s < 8; s++) {
                    FragU bh;
                    bh.q = *(const uint4*)(AhU + swz(s * 16 + nn, ks * 32 + q * 8));
                    acc[0][s] = __builtin_amdgcn_mfma_f32_16x16x32_f16(
                        wh[0].b, bh.b, acc[0][s], 0, 0, 0);
                    acc[1][s] = __builtin_amdgcn_mfma_f32_16x16x32_f16(
                        wh[1].b, bh.b, acc[1][s], 0, 0, 0);
                }
            }
            __syncthreads();   // all A reads done before overwrite
            #pragma unroll
            for (int i = 0; i < 2; i++) {
                const int ubase = (2 * wv + i) * 16 + q * 4;
                F4 bv; bv.v = *(const float4*)(bl + ubase);
                #pragma unroll
                for (int g = 0; g < 2; g++) {
                    float vals[4][4];
                    #pragma unroll
                    for (int r = 0; r < 4; r++) {
                        float z  = acc[i][g * 4 + 0][r] + bv.f[r];
                        float zx = acc[i][g * 4 + 1][r];
                        float zy = acc[i][g * 4 + 2][r];
                        float zl = acc[i][g * 4 + 3][r];
                        float tt = fast_tanh(z);
                        float s2 = 1.f - tt * tt;
                        float m2 = -2.f * tt * s2;
                        vals[0][r] = tt;
                        vals[1][r] = s2 * zx;
                        vals[2][r] = s2 * zy;
                        vals[3][r] = s2 * zl + m2 * (zx * zx + zy * zy);
                    }
                    #pragma unroll
                    for (int s = 0; s < 4; s++) {
                        uint2 d = make_uint2(pk2(vals[s][0], vals[s][1]),
                                             pk2(vals[s][2], vals[s][3]));
                        *(uint2*)(AhU + swz((g * 4 + s) * 16 + nn, ubase)) = d;
                    }
                }
            }
            __syncthreads();
        }

        // ---- layer 4 + residual: waves 0,1 own their point-group fully ----
        if (wv < 2) {
            const unsigned short* W4p = wsU + 102400;
            f32x4 a4[4];
            #pragma unroll
            for (int s = 0; s < 4; s++) {
                a4[s][0] = 0.f; a4[s][1] = 0.f; a4[s][2] = 0.f; a4[s][3] = 0.f;
            }
            #pragma unroll
            for (int ks = 0; ks < 4; ks++) {
                FragU wh, wl;
                const unsigned short* base = W4p + ((ks * 64 + lane) << 3);
                wh.q = *(const uint4*)base;
                wl.q = *(const uint4*)(base + 2048);
                #pragma unroll
                for (int s = 0; s < 4; s++) {
                    FragU bh;
                    bh.q = *(const uint4*)(AhU + swz((wv * 4 + s) * 16 + nn, ks * 32 + q * 8));
                    a4[s] = __builtin_amdgcn_mfma_f32_16x16x32_f16(wh.b, bh.b, a4[s], 0, 0, 0);
                    a4[s] = __builtin_amdgcn_mfma_f32_16x16x32_f16(wl.b, bh.b, a4[s], 0, 0, 0);
                }
            }
            float contrib = 0.f;
            if (q == 0) {
                float r  = a4[0][0] + b4[0], P = a4[0][1] + b4[1];
                float u  = a4[0][2] + b4[2], v = a4[0][3] + b4[3];
                float rx = a4[1][0], Px = a4[1][1], ux = a4[1][2], vx = a4[1][3];
                float ry = a4[2][0], Py = a4[2][1], uy = a4[2][2], vy = a4[2][3];
                float rl = a4[3][0], Pl = a4[3][1], ul = a4[3][2], vl = a4[3][3];
                const float GI = 2.5f;  // 1/(gamma-1)

                float q2 = u * u + v * v;
                float E  = P * GI + 0.5f * r * q2;
                float Ex = Px * GI + 0.5f * rx * q2 + r * (u * ux + v * vx);
                float Ey = Py * GI + 0.5f * ry * q2 + r * (u * uy + v * vy);
                float EpP = E + P;

                float f1x = rx * u + r * ux;
                float f2x = rx * u * u + 2.f * r * u * ux + Px;
                float f3x = rx * u * v + r * ux * v + r * u * vx;
                float f4x = ux * EpP + u * (Ex + Px);

                float g1y = ry * v + r * vy;
                float g2y = ry * u * v + r * uy * v + r * u * vy;
                float g3y = ry * v * v + 2.f * r * v * vy + Py;
                float g4y = vy * EpP + v * (Ey + Py);

                float qx  = 2.f * (u * ux + v * vx);
                float qy  = 2.f * (u * uy + v * vy);
                float ql  = 2.f * (ux * ux + uy * uy + vx * vx + vy * vy)
                          + 2.f * (u * ul + v * vl);

                float U1s = rl;
                float U2s = rl * u + 2.f * (rx * ux + ry * uy) + r * ul;
                float U3s = rl * v + 2.f * (rx * vx + ry * vy) + r * vl;
                float U4s = Pl * GI
                          + 0.5f * (rl * q2 + 2.f * (rx * qx + ry * qy) + r * ql);

                float r1 = f1x + g1y - mu * U1s;
                float r2 = f2x + g2y - mu * U2s;
                float r3 = f3x + g3y - mu * U3s;
                float r4 = f4x + g4y - mu * U4s;

                contrib = (r1 * r1 + r2 * r2 + r3 * r3 + r4 * r4 + 0.1f * mu * mu)
                          * (1.0f / (float)NTRAIN);
            }
            contrib += __shfl_down(contrib, 32);
            contrib += __shfl_down(contrib, 16);
            contrib += __shfl_down(contrib, 8);
            contrib += __shfl_down(contrib, 4);
            contrib += __shfl_down(contrib, 2);
            contrib += __shfl_down(contrib, 1);
            if (lane == 0) atomicAdd(out, contrib);
        }
    } else {
        // =================== BOUNDARY PATH (MFMA, 64 pts/block) ============
        const int bb    = blockIdx.x - PHYS_BLOCKS;
        const int batch = bb >> 6;  // 0..3 (64 blocks each)
        const int lb    = bb & 63;
        const float* xs = (batch == 0) ? x_inlet
                        : (batch == 1) ? x_base
                        : (batch == 2) ? x_top : x_slip;
        const int base_pt = lb * 64;

        // ---- layer 0: 2 -> 128 (4 threads/pt, 32 units each) ----
        {
            int p2 = t & 63, ug = t >> 6;
            float2 xy = *(const float2*)(xs + (base_pt + p2) * 2);
            float x = xy.x, y = xy.y;
            #pragma unroll
            for (int g = 0; g < 8; g++) {
                int u0 = ug * 32 + g * 4;
                F4 wa, wb, bbv;
                wa.v  = *(const float4*)(W0 + u0);
                wb.v  = *(const float4*)(W0 + 128 + u0);
                bbv.v = *(const float4*)(b0 + u0);
                float t0 = fast_tanh(x * wa.f[0] + y * wb.f[0] + bbv.f[0]);
                float t1 = fast_tanh(x * wa.f[1] + y * wb.f[1] + bbv.f[1]);
                float t2 = fast_tanh(x * wa.f[2] + y * wb.f[2] + bbv.f[2]);
                float t3 = fast_tanh(x * wa.f[3] + y * wb.f[3] + bbv.f[3]);
                uint2 d = make_uint2(pk2(t0, t1), pk2(t2, t3));
                *(uint2*)(AhU + swz(p2, u0)) = d;
            }
        }
        __syncthreads();

        // ---- hidden layers 1..3 via MFMA (W hi only, 4 point-tiles) ----
        #pragma unroll 1
        for (int l = 0; l < 3; l++) {
            const unsigned short* WpL = wsU + l * 32768;
            const float* bl = (l == 0) ? b1 : (l == 1) ? b2 : b3;
            f32x4 acc[2][4];
            #pragma unroll
            for (int i = 0; i < 2; i++)
                #pragma unroll
                for (int n = 0; n < 4; n++) {
                    acc[i][n][0] = 0.f; acc[i][n][1] = 0.f;
                    acc[i][n][2] = 0.f; acc[i][n][3] = 0.f;
                }
            #pragma unroll
            for (int ks = 0; ks < 4; ks++) {
                FragU bh[4];
                #pragma unroll
                for (int n = 0; n < 4; n++)
                    bh[n].q = *(const uint4*)(AhU + swz(n * 16 + nn, ks * 32 + q * 8));
                FragU wh[2];
                #pragma unroll
                for (int i = 0; i < 2; i++)
                    wh[i].q = *(const uint4*)(WpL + ((((2 * wv + i) * 4 + ks) * 64 + lane) << 3));
                #pragma unroll
                for (int i = 0; i < 2; i++)
                    #pragma unroll
                    for (int n = 0; n < 4; n++)
                        acc[i][n] = __builtin_amdgcn_mfma_f32_16x16x32_f16(
                            wh[i].b, bh[n].b, acc[i][n], 0, 0, 0);
            }
            __syncthreads();
            #pragma unroll
            for (int i = 0; i < 2; i++) {
                int ubase = (2 * wv + i) * 16 + q * 4;
                F4 bv; bv.v = *(const float4*)(bl + ubase);
                #pragma unroll
                for (int n = 0; n < 4; n++) {
                    float t0 = fast_tanh(acc[i][n][0] + bv.f[0]);
                    float t1 = fast_tanh(acc[i][n][1] + bv.f[1]);
                    float t2 = fast_tanh(acc[i][n][2] + bv.f[2]);
                    float t3 = fast_tanh(acc[i][n][3] + bv.f[3]);
                    uint2 d = make_uint2(pk2(t0, t1), pk2(t2, t3));
                    *(uint2*)(AhU + swz(n * 16 + nn, ubase)) = d;
                }
            }
            __syncthreads();
        }

        // ---- layer 4 (padded W4, hi+lo), tile wv = own points; loss local --
        {
            const unsigned short* W4p = wsU + 102400;
            f32x4 a4 = {0.f, 0.f, 0.f, 0.f};
            #pragma unroll
            for (int ks = 0; ks < 4; ks++) {
                FragU bh, wh, wl;
                bh.q = *(const uint4*)(AhU + swz(wv * 16 + nn, ks * 32 + q * 8));
                const unsigned short* base = W4p + ((ks * 64 + lane) << 3);
                wh.q = *(const uint4*)base;
                wl.q = *(const uint4*)(base + 2048);
                a4 = __builtin_amdgcn_mfma_f32_16x16x32_f16(wh.b, bh.b, a4, 0, 0, 0);
                a4 = __builtin_amdgcn_mfma_f32_16x16x32_f16(wl.b, bh.b, a4, 0, 0, 0);
            }
            float contrib = 0.f;
            if (q == 0) {
                float o0 = a4[0] + b4[0], o1 = a4[1] + b4[1];
                float o2 = a4[2] + b4[2], o3 = a4[3] + b4[3];
                float l;
                if (batch == 0) {
                    float4 Ui = *(const float4*)(U_inlet + (base_pt + wv * 16 + nn) * 4);
                    float d0 = o0 - Ui.x, d1 = o1 - Ui.y, d2 = o2 - Ui.z, d3 = o3 - Ui.w;
                    l = d0 * d0 + d1 * d1 + d2 * d2 + d3 * d3;
                } else if (batch == 3) {
                    const float sa = -0.17364817766693033f;  // sin(-pi/18)
                    const float ca =  0.9848077530122080f;   // cos(-pi/18)
                    float d = -o2 * sa + o3 * ca;
                    l = d * d;
                } else {
                    l = o3 * o3;
                }
                contrib = 10.0f * l * (1.0f / (float)NBDY);
            }
            contrib += __shfl_down(contrib, 32);
            contrib += __shfl_down(contrib, 16);
            contrib += __shfl_down(contrib, 8);
            contrib += __shfl_down(contrib, 4);
            contrib += __shfl_down(contrib, 2);
            contrib += __shfl_down(contrib, 1);
            if (lane == 0) atomicAdd(out, contrib);
        }
    }
}

extern "C" void kernel_launch(void* const* d_in, const int* in_sizes, int n_in,
                              void* d_out, int out_size, void* d_ws, size_t ws_size,
                              hipStream_t stream) {
    const float* xt      = (const float*)d_in[0];
    const float* x_inlet = (const float*)d_in[1];
    const float* U_inlet = (const float*)d_in[2];
    const float* x_base  = (const float*)d_in[3];
    const float* x_top   = (const float*)d_in[4];
    const float* x_slip  = (const float*)d_in[5];
    const float* W0 = (const float*)d_in[6];
    const float* b0 = (const float*)d_in[7];
    const float* W1 = (const float*)d_in[8];
    const float* b1 = (const float*)d_in[9];
    const float* W2 = (const float*)d_in[10];
    const float* b2 = (const float*)d_in[11];
    const float* W3 = (const float*)d_in[12];
    const float* b3 = (const float*)d_in[13];
    const float* W4 = (const float*)d_in[14];
    const float* b4 = (const float*)d_in[15];
    const float* V0 = (const float*)d_in[16];
    const float* c0 = (const float*)d_in[17];
    const float* V1 = (const float*)d_in[18];
    const float* c1 = (const float*)d_in[19];
    const float* V2 = (const float*)d_in[20];
    const float* c2 = (const float*)d_in[21];
    float* out = (float*)d_out;
    unsigned short* wsU = (unsigned short*)d_ws;

    pack_w_kernel<<<26, 256, 0, stream>>>(W1, W2, W3, V1, W4, wsU, out);

    fused_kernel<<<PHYS_BLOCKS + BDY_BLOCKS, 256, 0, stream>>>(
        xt, x_inlet, U_inlet, x_base, x_top, x_slip,
        W0, b0, W1, b1, W2, b2, W3, b3, W4, b4,
        V0, c0, V1, c1, V2, c2, wsU, out);
}

// Round 9
// 131.481 us; speedup vs baseline: 1.5234x; 1.4282x over previous
//
#include <hip/hip_runtime.h>

#define NTRAIN 32768
#define NBDY   4096
#define PHYS_BLOCKS (NTRAIN / 32)   // 1024 blocks, 32 pts each
#define BDY_BLOCKS  256             // 64 pts/block, 64 blocks per batch

typedef _Float16 f16x8 __attribute__((ext_vector_type(8)));
typedef __fp16   fp16x2 __attribute__((ext_vector_type(2)));
typedef float    f32x4 __attribute__((ext_vector_type(4)));

union FragU { uint4 q; f16x8 b; _Float16 e[8]; };
union F4  { float4 v; float f[4]; };
union H2  { fp16x2 h; _Float16 e[2]; unsigned int u; };

__device__ __forceinline__ float fast_tanh(float z) {
    float e = __expf(2.0f * z);
    return 1.0f - 2.0f * __builtin_amdgcn_rcpf(e + 1.0f);
}

__device__ __forceinline__ unsigned int pk2(float a, float b) {
    H2 r; r.h = __builtin_amdgcn_cvt_pkrtz(a, b);
    return r.u;
}

// ---------------------------------------------------------------------------
// Pack weights into MFMA A-fragment order (fp16 hi+lo).
// W1..W3: hi at wsU + l*32768, lo at +16384 (lo unused by fused hidden layers).
// V1-hi at wsU+98304. W4 padded 128x16: hi at wsU+102400, lo +2048.
// Block 24 zeroes out[0].
// ---------------------------------------------------------------------------
__global__ __launch_bounds__(256) void pack_w_kernel(
    const float* __restrict__ W1, const float* __restrict__ W2,
    const float* __restrict__ W3, const float* __restrict__ V1,
    const float* __restrict__ W4,
    unsigned short* __restrict__ wsU, float* __restrict__ out)
{
    int b = blockIdx.x;
    if (b < 24) {
        int mat = b >> 3, rb = b & 7;          // 16 rows per block
        const float* W = (mat == 0) ? W1 : (mat == 1) ? W2 : W3;
        unsigned int* hiU = (unsigned int*)(wsU + mat * 32768);
        unsigned int* loU = hiU + 8192;
        int n   = threadIdx.x & 127;
        int pr0 = threadIdx.x >> 7;
        #pragma unroll
        for (int it = 0; it < 4; it++) {
            int pr = pr0 + 2 * it;
            int k  = rb * 16 + pr * 2;
            float v0 = W[k * 128 + n];
            float v1 = W[(k + 1) * 128 + n];
            H2 hh, ll;
            hh.e[0] = (_Float16)v0;
            hh.e[1] = (_Float16)v1;
            ll.e[0] = (_Float16)(v0 - (float)hh.e[0]);
            ll.e[1] = (_Float16)(v1 - (float)hh.e[1]);
            int base = ((n >> 4) * 4 + (k >> 5)) * 64 + ((k >> 3) & 3) * 16 + (n & 15);
            int uoff = base * 4 + ((k & 7) >> 1);
            hiU[uoff] = hh.u;
            loU[uoff] = ll.u;
        }
    } else if (b == 24) {
        unsigned int* hiU = (unsigned int*)(wsU + 98304);
        int n   = threadIdx.x & 63;
        int pr0 = threadIdx.x >> 6;
        #pragma unroll
        for (int it = 0; it < 8; it++) {
            int pr = pr0 + 4 * it;
            int k  = pr * 2;
            float v0 = V1[k * 64 + n];
            float v1 = V1[(k + 1) * 64 + n];
            H2 hh;
            hh.e[0] = (_Float16)v0;
            hh.e[1] = (_Float16)v1;
            int base = ((n >> 4) * 2 + (k >> 5)) * 64 + ((k >> 3) & 3) * 16 + (n & 15);
            hiU[base * 4 + ((k & 7) >> 1)] = hh.u;
        }
        if (threadIdx.x == 0) out[0] = 0.f;
    } else {
        _Float16* hi = (_Float16*)(wsU + 102400);
        _Float16* lo = hi + 2048;
        int u4 = threadIdx.x;
        int lane = u4 & 63, ks = u4 >> 6;
        int m  = lane & 15;
        int kb = ks * 32 + ((lane >> 4) << 3);
        FragU fh, fl;
        #pragma unroll
        for (int j = 0; j < 8; j++) {
            float v = (m < 4) ? W4[(kb + j) * 4 + m] : 0.f;
            _Float16 h = (_Float16)v;
            fh.e[j] = h;
            fl.e[j] = (_Float16)(v - (float)h);
        }
        *(uint4*)(hi + u4 * 8) = fh.q;
        *(uint4*)(lo + u4 * 8) = fl.q;
    }
}

// ---------------------------------------------------------------------------
// Fused kernel, r26 = exact restore of r18 (session champion, 39.6 us fused,
// reproduced twice). 32-pt physics blocks, 256 threads / 4 waves.
// A-matrix = 128 MFMA rows (2 point-groups x 4 AD streams x 16 pts).
// Per wave: 2 unit-tiles x 8 row-tiles x 4 K-steps = 64 MFMAs/layer.
// LDS 38,912 B static -> 4 blocks/CU; true reg footprint ~64 VGPR + 64 AGPR
// = 128/thread (unified file) -> also 4 blocks/CU reg-wise. The two caps
// coincide; occupancy levers beyond this were all measured negative
// (r19-r25 post-mortems).
// Blocks [0,1024): physics. Blocks [1024,1280): boundary (64 pts each,
// short blocks last = cheap dispatch tail).
// ---------------------------------------------------------------------------
__global__ __launch_bounds__(256, 4) void fused_kernel(
    const float* __restrict__ xt,
    const float* __restrict__ x_inlet, const float* __restrict__ U_inlet,
    const float* __restrict__ x_base,  const float* __restrict__ x_top,
    const float* __restrict__ x_slip,
    const float* __restrict__ W0, const float* __restrict__ b0,
    const float* __restrict__ W1, const float* __restrict__ b1,
    const float* __restrict__ W2, const float* __restrict__ b2,
    const float* __restrict__ W3, const float* __restrict__ b3,
    const float* __restrict__ W4, const float* __restrict__ b4,
    const float* __restrict__ V0, const float* __restrict__ c0,
    const float* __restrict__ V1, const float* __restrict__ c1,
    const float* __restrict__ V2, const float* __restrict__ c2,
    const unsigned short* __restrict__ wsU,
    float* __restrict__ out)
{
    __shared__ float SM[9664];   // 38,656 B
    const int t = threadIdx.x;
    const int wv   = t >> 6;
    const int lane = t & 63;
    const int nn   = lane & 15;
    const int q    = lane >> 4;

    if (blockIdx.x < PHYS_BLOCKS) {
        // =================== PHYSICS PATH (32 pts) ===================
        unsigned short* AhU = (unsigned short*)SM;   // 128 rows x 136 ushorts
        float* OUTF   = SM + 8704;   // 128 x 4
        float* MUPART = SM + 9216;   // 64
        float* BIASF  = SM + 9280;   // 384 floats

        const int blk = blockIdx.x;

        if (t < 128) {
            BIASF[t]       = b1[t];
            BIASF[128 + t] = b2[t];
            BIASF[256 + t] = b3[t];
        }

        // ---- mu net: wave wv -> point-group g = wv>>1, unit-half h = wv&1 --
        {
            const int g = wv >> 1, h = wv & 1;
            const float2 xyn = *(const float2*)(xt + (blk * 32 + g * 16 + nn) * 2);
            FragU mb[2];
            #pragma unroll
            for (int ks = 0; ks < 2; ks++) {
                int u0 = ks * 32 + q * 8;
                F4 va0, va1, vb0, vb1, cc0, cc1;
                va0.v = *(const float4*)(V0 + u0);
                va1.v = *(const float4*)(V0 + u0 + 4);
                vb0.v = *(const float4*)(V0 + 64 + u0);
                vb1.v = *(const float4*)(V0 + 64 + u0 + 4);
                cc0.v = *(const float4*)(c0 + u0);
                cc1.v = *(const float4*)(c0 + u0 + 4);
                #pragma unroll
                for (int i = 0; i < 4; i++) {
                    mb[ks].e[i]     = (_Float16)fast_tanh(
                        xyn.x * va0.f[i] + xyn.y * vb0.f[i] + cc0.f[i]);
                    mb[ks].e[4 + i] = (_Float16)fast_tanh(
                        xyn.x * va1.f[i] + xyn.y * vb1.f[i] + cc1.f[i]);
                }
            }
            float partial = 0.f;
            #pragma unroll
            for (int i = 0; i < 2; i++) {
                f32x4 macc = {0.f, 0.f, 0.f, 0.f};
                #pragma unroll
                for (int ks = 0; ks < 2; ks++) {
                    FragU vh;
                    vh.q = *(const uint4*)(wsU + 98304 +
                           ((((2 * h + i) * 2 + ks) * 64 + lane) << 3));
                    macc = __builtin_amdgcn_mfma_f32_16x16x32_f16(vh.b, mb[ks].b, macc, 0, 0, 0);
                }
                int u2 = (2 * h + i) * 16 + q * 4;
                F4 cv, w2;
                cv.v = *(const float4*)(c1 + u2);
                w2.v = *(const float4*)(V2 + u2);
                #pragma unroll
                for (int r = 0; r < 4; r++)
                    partial += fast_tanh(macc[r] + cv.f[r]) * w2.f[r];
            }
            partial += __shfl_xor(partial, 16);
            partial += __shfl_xor(partial, 32);
            if (lane < 16) MUPART[wv * 16 + nn] = partial;
        }
        {   // main layer 0: 2 -> 128, 4 streams, 2 point-halves per thread
            const int pl = t >> 4, c = t & 15;
            #pragma unroll
            for (int h2 = 0; h2 < 2; h2++) {
                const int p = h2 * 16 + pl;
                const float2 xy = *(const float2*)(xt + (blk * 32 + p) * 2);
                const float x = xy.x, y = xy.y;
                float vals[4][8];
                #pragma unroll
                for (int j = 0; j < 8; j++) {
                    int u = c * 8 + j;
                    float w0 = W0[u], w1 = W0[128 + u];
                    float zv = x * w0 + y * w1 + b0[u];
                    float tt = fast_tanh(zv);
                    float s2 = 1.f - tt * tt;
                    float m2 = -2.f * tt * s2;
                    vals[0][j] = tt;
                    vals[1][j] = s2 * w0;
                    vals[2][j] = s2 * w1;
                    vals[3][j] = m2 * (w0 * w0 + w1 * w1);  // z_lap = 0 at layer 0
                }
                #pragma unroll
                for (int s = 0; s < 4; s++) {
                    uint4 d = make_uint4(pk2(vals[s][0], vals[s][1]),
                                         pk2(vals[s][2], vals[s][3]),
                                         pk2(vals[s][4], vals[s][5]),
                                         pk2(vals[s][6], vals[s][7]));
                    *(uint4*)(AhU + ((h2 * 4 + s) * 16 + pl) * 136 + c * 8) = d;
                }
            }
        }
        __syncthreads();

        // ------- hidden layers 1..3 via MFMA (8 row-tiles, W-hi 1-pass) ----
        #pragma unroll 1
        for (int l = 0; l < 3; l++) {
            const unsigned short* WpL = wsU + l * 32768;
            f32x4 acc[2][8];
            #pragma unroll
            for (int i = 0; i < 2; i++)
                #pragma unroll
                for (int s = 0; s < 8; s++) {
                    acc[i][s][0] = 0.f; acc[i][s][1] = 0.f;
                    acc[i][s][2] = 0.f; acc[i][s][3] = 0.f;
                }
            #pragma unroll
            for (int ks = 0; ks < 4; ks++) {
                FragU wh[2];
                #pragma unroll
                for (int i = 0; i < 2; i++)
                    wh[i].q = *(const uint4*)(WpL + ((((2 * wv + i) * 4 + ks) * 64 + lane) << 3));
                #pragma unroll
                for (int s = 0; s < 8; s++) {
                    FragU bh;
                    bh.q = *(const uint4*)(AhU + (s * 16 + nn) * 136 + ks * 32 + q * 8);
                    acc[0][s] = __builtin_amdgcn_mfma_f32_16x16x32_f16(
                        wh[0].b, bh.b, acc[0][s], 0, 0, 0);
                    acc[1][s] = __builtin_amdgcn_mfma_f32_16x16x32_f16(
                        wh[1].b, bh.b, acc[1][s], 0, 0, 0);
                }
            }
            __syncthreads();   // all A reads done before overwrite
            #pragma unroll
            for (int i = 0; i < 2; i++) {
                const int ubase = (2 * wv + i) * 16 + q * 4;
                F4 bv; bv.v = *(const float4*)&BIASF[l * 128 + ubase];
                #pragma unroll
                for (int g = 0; g < 2; g++) {
                    float vals[4][4];
                    #pragma unroll
                    for (int r = 0; r < 4; r++) {
                        float z  = acc[i][g * 4 + 0][r] + bv.f[r];
                        float zx = acc[i][g * 4 + 1][r];
                        float zy = acc[i][g * 4 + 2][r];
                        float zl = acc[i][g * 4 + 3][r];
                        float tt = fast_tanh(z);
                        float s2 = 1.f - tt * tt;
                        float m2 = -2.f * tt * s2;
                        vals[0][r] = tt;
                        vals[1][r] = s2 * zx;
                        vals[2][r] = s2 * zy;
                        vals[3][r] = s2 * zl + m2 * (zx * zx + zy * zy);
                    }
                    #pragma unroll
                    for (int s = 0; s < 4; s++) {
                        uint2 d = make_uint2(pk2(vals[s][0], vals[s][1]),
                                             pk2(vals[s][2], vals[s][3]));
                        *(uint2*)(AhU + ((g * 4 + s) * 16 + nn) * 136 + ubase) = d;
                    }
                }
            }
            __syncthreads();
        }

        // ---------------- layer 4: 128 -> 4 via MFMA (padded W4, hi+lo) ----
        {
            const unsigned short* W4p = wsU + 102400;
            const int rtA = wv, rtB = 4 + wv;
            f32x4 aA = {0.f, 0.f, 0.f, 0.f};
            f32x4 aB = {0.f, 0.f, 0.f, 0.f};
            #pragma unroll
            for (int ks = 0; ks < 4; ks++) {
                FragU wh, wl, bA, bB;
                const unsigned short* base = W4p + ((ks * 64 + lane) << 3);
                wh.q = *(const uint4*)base;
                wl.q = *(const uint4*)(base + 2048);
                bA.q = *(const uint4*)(AhU + (rtA * 16 + nn) * 136 + ks * 32 + q * 8);
                bB.q = *(const uint4*)(AhU + (rtB * 16 + nn) * 136 + ks * 32 + q * 8);
                aA = __builtin_amdgcn_mfma_f32_16x16x32_f16(wh.b, bA.b, aA, 0, 0, 0);
                aA = __builtin_amdgcn_mfma_f32_16x16x32_f16(wl.b, bA.b, aA, 0, 0, 0);
                aB = __builtin_amdgcn_mfma_f32_16x16x32_f16(wh.b, bB.b, aB, 0, 0, 0);
                aB = __builtin_amdgcn_mfma_f32_16x16x32_f16(wl.b, bB.b, aB, 0, 0, 0);
            }
            if (q == 0) {
                float4 oA = make_float4(aA[0], aA[1], aA[2], aA[3]);
                float4 oB = make_float4(aB[0], aB[1], aB[2], aB[3]);
                if (wv == 0) {   // rtA==0 / rtB==4 are the value streams
                    oA.x += b4[0]; oA.y += b4[1]; oA.z += b4[2]; oA.w += b4[3];
                    oB.x += b4[0]; oB.y += b4[1]; oB.z += b4[2]; oB.w += b4[3];
                }
                *(float4*)&OUTF[(rtA * 16 + nn) * 4] = oA;
                *(float4*)&OUTF[(rtB * 16 + nn) * 4] = oB;
            }
        }
        __syncthreads();

        // ---------------- per-point residual + reduction -------------------
        float contrib = 0.f;
        if (t < 32) {
            const int pp = t, g = pp >> 4, p15 = pp & 15;
            const float* V   = &OUTF[((g * 4 + 0) * 16 + p15) * 4];
            const float* DX  = &OUTF[((g * 4 + 1) * 16 + p15) * 4];
            const float* DY  = &OUTF[((g * 4 + 2) * 16 + p15) * 4];
            const float* LAP = &OUTF[((g * 4 + 3) * 16 + p15) * 4];
            float r = V[0],  P = V[1],  u = V[2],  v = V[3];
            float rx = DX[0], Px = DX[1], ux = DX[2], vx = DX[3];
            float ry = DY[0], Py = DY[1], uy = DY[2], vy = DY[3];
            float rl = LAP[0], Pl = LAP[1], ul = LAP[2], vl = LAP[3];
            const float GI = 2.5f;  // 1/(gamma-1)

            float s = MUPART[(2 * g) * 16 + p15] + MUPART[(2 * g + 1) * 16 + p15]
                    + c2[0];
            float mu = 0.01f * s * s;

            float q2 = u * u + v * v;
            float E  = P * GI + 0.5f * r * q2;
            float Ex = Px * GI + 0.5f * rx * q2 + r * (u * ux + v * vx);
            float Ey = Py * GI + 0.5f * ry * q2 + r * (u * uy + v * vy);
            float EpP = E + P;

            float f1x = rx * u + r * ux;
            float f2x = rx * u * u + 2.f * r * u * ux + Px;
            float f3x = rx * u * v + r * ux * v + r * u * vx;
            float f4x = ux * EpP + u * (Ex + Px);

            float g1y = ry * v + r * vy;
            float g2y = ry * u * v + r * uy * v + r * u * vy;
            float g3y = ry * v * v + 2.f * r * v * vy + Py;
            float g4y = vy * EpP + v * (Ey + Py);

            float qx  = 2.f * (u * ux + v * vx);
            float qy  = 2.f * (u * uy + v * vy);
            float ql  = 2.f * (ux * ux + uy * uy + vx * vx + vy * vy)
                      + 2.f * (u * ul + v * vl);

            float U1s = rl;
            float U2s = rl * u + 2.f * (rx * ux + ry * uy) + r * ul;
            float U3s = rl * v + 2.f * (rx * vx + ry * vy) + r * vl;
            float U4s = Pl * GI
                      + 0.5f * (rl * q2 + 2.f * (rx * qx + ry * qy) + r * ql);

            float r1 = f1x + g1y - mu * U1s;
            float r2 = f2x + g2y - mu * U2s;
            float r3 = f3x + g3y - mu * U3s;
            float r4 = f4x + g4y - mu * U4s;

            contrib = (r1 * r1 + r2 * r2 + r3 * r3 + r4 * r4 + 0.1f * mu * mu)
                      * (1.0f / (float)NTRAIN);
        }
        if (t < 64) {
            contrib += __shfl_down(contrib, 32);
            contrib += __shfl_down(contrib, 16);
            contrib += __shfl_down(contrib, 8);
            contrib += __shfl_down(contrib, 4);
            contrib += __shfl_down(contrib, 2);
            contrib += __shfl_down(contrib, 1);
            if (t == 0) atomicAdd(out, contrib);
        }
    } else {
        // =================== BOUNDARY PATH (MFMA, 64 pts/block) ============
        unsigned short* ShU = (unsigned short*)SM;   // 64 x 136
        float* OUTB  = SM + 4352;   // 64 x 4
        float* BIASB = SM + 4608;   // 384 floats

        const int bb    = blockIdx.x - PHYS_BLOCKS;
        const int batch = bb >> 6;  // 0..3 (64 blocks each)
        const int lb    = bb & 63;
        const float* xs = (batch == 0) ? x_inlet
                        : (batch == 1) ? x_base
                        : (batch == 2) ? x_top : x_slip;
        const int base_pt = lb * 64;

        // ---- layer 0: 2 -> 128 (4 threads/pt, 32 units each) + biases ----
        {
            int p2 = t & 63, ug = t >> 6;
            float2 xy = *(const float2*)(xs + (base_pt + p2) * 2);
            float x = xy.x, y = xy.y;
            #pragma unroll
            for (int g = 0; g < 8; g++) {
                int u0 = ug * 32 + g * 4;
                F4 wa, wb, bbv;
                wa.v  = *(const float4*)(W0 + u0);
                wb.v  = *(const float4*)(W0 + 128 + u0);
                bbv.v = *(const float4*)(b0 + u0);
                float t0 = fast_tanh(x * wa.f[0] + y * wb.f[0] + bbv.f[0]);
                float t1 = fast_tanh(x * wa.f[1] + y * wb.f[1] + bbv.f[1]);
                float t2 = fast_tanh(x * wa.f[2] + y * wb.f[2] + bbv.f[2]);
                float t3 = fast_tanh(x * wa.f[3] + y * wb.f[3] + bbv.f[3]);
                uint2 d = make_uint2(pk2(t0, t1), pk2(t2, t3));
                *(uint2*)(ShU + p2 * 136 + u0) = d;
            }
            if (t < 128) {
                BIASB[t]       = b1[t];
                BIASB[128 + t] = b2[t];
                BIASB[256 + t] = b3[t];
            }
        }
        __syncthreads();

        // ---- hidden layers 1..3 via MFMA (W hi only, 4 point-tiles) ----
        #pragma unroll 1
        for (int l = 0; l < 3; l++) {
            const unsigned short* WpL = wsU + l * 32768;
            f32x4 acc[2][4];
            #pragma unroll
            for (int i = 0; i < 2; i++)
                #pragma unroll
                for (int n = 0; n < 4; n++) {
                    acc[i][n][0] = 0.f; acc[i][n][1] = 0.f;
                    acc[i][n][2] = 0.f; acc[i][n][3] = 0.f;
                }
            #pragma unroll
            for (int ks = 0; ks < 4; ks++) {
                FragU bh[4];
                #pragma unroll
                for (int n = 0; n < 4; n++)
                    bh[n].q = *(const uint4*)(ShU + (n * 16 + nn) * 136 + ks * 32 + q * 8);
                FragU wh[2];
                #pragma unroll
                for (int i = 0; i < 2; i++)
                    wh[i].q = *(const uint4*)(WpL + ((((2 * wv + i) * 4 + ks) * 64 + lane) << 3));
                #pragma unroll
                for (int i = 0; i < 2; i++)
                    #pragma unroll
                    for (int n = 0; n < 4; n++)
                        acc[i][n] = __builtin_amdgcn_mfma_f32_16x16x32_f16(
                            wh[i].b, bh[n].b, acc[i][n], 0, 0, 0);
            }
            __syncthreads();
            #pragma unroll
            for (int i = 0; i < 2; i++) {
                int ubase = (2 * wv + i) * 16 + q * 4;
                F4 bv; bv.v = *(const float4*)&BIASB[l * 128 + ubase];
                #pragma unroll
                for (int n = 0; n < 4; n++) {
                    float t0 = fast_tanh(acc[i][n][0] + bv.f[0]);
                    float t1 = fast_tanh(acc[i][n][1] + bv.f[1]);
                    float t2 = fast_tanh(acc[i][n][2] + bv.f[2]);
                    float t3 = fast_tanh(acc[i][n][3] + bv.f[3]);
                    uint2 d = make_uint2(pk2(t0, t1), pk2(t2, t3));
                    *(uint2*)(ShU + (n * 16 + nn) * 136 + ubase) = d;
                }
            }
            __syncthreads();
        }

        // ---- layer 4 via MFMA (padded W4, hi+lo), one point-tile/wave ----
        {
            const unsigned short* W4p = wsU + 102400;
            f32x4 a4 = {0.f, 0.f, 0.f, 0.f};
            #pragma unroll
            for (int ks = 0; ks < 4; ks++) {
                FragU bh, wh, wl;
                bh.q = *(const uint4*)(ShU + (wv * 16 + nn) * 136 + ks * 32 + q * 8);
                const unsigned short* base = W4p + ((ks * 64 + lane) << 3);
                wh.q = *(const uint4*)base;
                wl.q = *(const uint4*)(base + 2048);
                a4 = __builtin_amdgcn_mfma_f32_16x16x32_f16(wh.b, bh.b, a4, 0, 0, 0);
                a4 = __builtin_amdgcn_mfma_f32_16x16x32_f16(wl.b, bh.b, a4, 0, 0, 0);
            }
            if (q == 0) {
                float4 o = make_float4(a4[0] + b4[0], a4[1] + b4[1],
                                       a4[2] + b4[2], a4[3] + b4[3]);
                *(float4*)&OUTB[(wv * 16 + nn) * 4] = o;
            }
        }
        __syncthreads();

        float contrib = 0.f;
        if (t < 64) {
            float o0 = OUTB[t * 4 + 0], o1 = OUTB[t * 4 + 1];
            float o2 = OUTB[t * 4 + 2], o3 = OUTB[t * 4 + 3];
            float l;
            if (batch == 0) {
                float4 Ui = *(const float4*)(U_inlet + (base_pt + t) * 4);
                float d0 = o0 - Ui.x, d1 = o1 - Ui.y, d2 = o2 - Ui.z, d3 = o3 - Ui.w;
                l = d0 * d0 + d1 * d1 + d2 * d2 + d3 * d3;
            } else if (batch == 3) {
                const float sa = -0.17364817766693033f;  // sin(-pi/18)
                const float ca =  0.9848077530122080f;   // cos(-pi/18)
                float d = -o2 * sa + o3 * ca;
                l = d * d;
            } else {
                l = o3 * o3;
            }
            contrib = 10.0f * l * (1.0f / (float)NBDY);
        }
        if (t < 64) {
            contrib += __shfl_down(contrib, 32);
            contrib += __shfl_down(contrib, 16);
            contrib += __shfl_down(contrib, 8);
            contrib += __shfl_down(contrib, 4);
            contrib += __shfl_down(contrib, 2);
            contrib += __shfl_down(contrib, 1);
            if (t == 0) atomicAdd(out, contrib);
        }
    }
}

extern "C" void kernel_launch(void* const* d_in, const int* in_sizes, int n_in,
                              void* d_out, int out_size, void* d_ws, size_t ws_size,
                              hipStream_t stream) {
    const float* xt      = (const float*)d_in[0];
    const float* x_inlet = (const float*)d_in[1];
    const float* U_inlet = (const float*)d_in[2];
    const float* x_base  = (const float*)d_in[3];
    const float* x_top   = (const float*)d_in[4];
    const float* x_slip  = (const float*)d_in[5];
    const float* W0 = (const float*)d_in[6];
    const float* b0 = (const float*)d_in[7];
    const float* W1 = (const float*)d_in[8];
    const float* b1 = (const float*)d_in[9];
    const float* W2 = (const float*)d_in[10];
    const float* b2 = (const float*)d_in[11];
    const float* W3 = (const float*)d_in[12];
    const float* b3 = (const float*)d_in[13];
    const float* W4 = (const float*)d_in[14];
    const float* b4 = (const float*)d_in[15];
    const float* V0 = (const float*)d_in[16];
    const float* c0 = (const float*)d_in[17];
    const float* V1 = (const float*)d_in[18];
    const float* c1 = (const float*)d_in[19];
    const float* V2 = (const float*)d_in[20];
    const float* c2 = (const float*)d_in[21];
    float* out = (float*)d_out;
    unsigned short* wsU = (unsigned short*)d_ws;

    pack_w_kernel<<<26, 256, 0, stream>>>(W1, W2, W3, V1, W4, wsU, out);

    fused_kernel<<<PHYS_BLOCKS + BDY_BLOCKS, 256, 0, stream>>>(
        xt, x_inlet, U_inlet, x_base, x_top, x_slip,
        W0, b0, W1, b1, W2, b2, W3, b3, W4, b4,
        V0, c0, V1, c1, V2, c2, wsU, out);
}

// Round 10
// 128.533 us; speedup vs baseline: 1.5583x; 1.0229x over previous
//
#include <hip/hip_runtime.h>

#define NTRAIN 32768
#define NBDY   4096
#define PHYS_BLOCKS (NTRAIN / 32)   // 1024 blocks, 32 pts each
#define BDY_BLOCKS  256             // 64 pts/block, 64 blocks per batch

typedef _Float16 f16x8 __attribute__((ext_vector_type(8)));
typedef __fp16   fp16x2 __attribute__((ext_vector_type(2)));
typedef float    f32x4 __attribute__((ext_vector_type(4)));

union FragU { uint4 q; f16x8 b; _Float16 e[8]; };
union F4  { float4 v; float f[4]; };
union H2  { fp16x2 h; _Float16 e[2]; unsigned int u; };

__device__ __forceinline__ float fast_tanh(float z) {
    float e = __expf(2.0f * z);
    return 1.0f - 2.0f * __builtin_amdgcn_rcpf(e + 1.0f);
}

__device__ __forceinline__ unsigned int pk2(float a, float b) {
    H2 r; r.h = __builtin_amdgcn_cvt_pkrtz(a, b);
    return r.u;
}

// ---------------------------------------------------------------------------
// Pack weights into MFMA A-fragment order (fp16 hi+lo).
// W1..W3: hi at wsU + l*32768, lo at +16384 (lo unused by fused hidden layers).
// V1-hi at wsU+98304. W4 padded 128x16: hi at wsU+102400, lo +2048.
// Block 24 zeroes out[0].
// ---------------------------------------------------------------------------
__global__ __launch_bounds__(256) void pack_w_kernel(
    const float* __restrict__ W1, const float* __restrict__ W2,
    const float* __restrict__ W3, const float* __restrict__ V1,
    const float* __restrict__ W4,
    unsigned short* __restrict__ wsU, float* __restrict__ out)
{
    int b = blockIdx.x;
    if (b < 24) {
        int mat = b >> 3, rb = b & 7;          // 16 rows per block
        const float* W = (mat == 0) ? W1 : (mat == 1) ? W2 : W3;
        unsigned int* hiU = (unsigned int*)(wsU + mat * 32768);
        unsigned int* loU = hiU + 8192;
        int n   = threadIdx.x & 127;
        int pr0 = threadIdx.x >> 7;
        #pragma unroll
        for (int it = 0; it < 4; it++) {
            int pr = pr0 + 2 * it;
            int k  = rb * 16 + pr * 2;
            float v0 = W[k * 128 + n];
            float v1 = W[(k + 1) * 128 + n];
            H2 hh, ll;
            hh.e[0] = (_Float16)v0;
            hh.e[1] = (_Float16)v1;
            ll.e[0] = (_Float16)(v0 - (float)hh.e[0]);
            ll.e[1] = (_Float16)(v1 - (float)hh.e[1]);
            int base = ((n >> 4) * 4 + (k >> 5)) * 64 + ((k >> 3) & 3) * 16 + (n & 15);
            int uoff = base * 4 + ((k & 7) >> 1);
            hiU[uoff] = hh.u;
            loU[uoff] = ll.u;
        }
    } else if (b == 24) {
        unsigned int* hiU = (unsigned int*)(wsU + 98304);
        int n   = threadIdx.x & 63;
        int pr0 = threadIdx.x >> 6;
        #pragma unroll
        for (int it = 0; it < 8; it++) {
            int pr = pr0 + 4 * it;
            int k  = pr * 2;
            float v0 = V1[k * 64 + n];
            float v1 = V1[(k + 1) * 64 + n];
            H2 hh;
            hh.e[0] = (_Float16)v0;
            hh.e[1] = (_Float16)v1;
            int base = ((n >> 4) * 2 + (k >> 5)) * 64 + ((k >> 3) & 3) * 16 + (n & 15);
            hiU[base * 4 + ((k & 7) >> 1)] = hh.u;
        }
        if (threadIdx.x == 0) out[0] = 0.f;
    } else {
        _Float16* hi = (_Float16*)(wsU + 102400);
        _Float16* lo = hi + 2048;
        int u4 = threadIdx.x;
        int lane = u4 & 63, ks = u4 >> 6;
        int m  = lane & 15;
        int kb = ks * 32 + ((lane >> 4) << 3);
        FragU fh, fl;
        #pragma unroll
        for (int j = 0; j < 8; j++) {
            float v = (m < 4) ? W4[(kb + j) * 4 + m] : 0.f;
            _Float16 h = (_Float16)v;
            fh.e[j] = h;
            fl.e[j] = (_Float16)(v - (float)h);
        }
        *(uint4*)(hi + u4 * 8) = fh.q;
        *(uint4*)(lo + u4 * 8) = fl.q;
    }
}

// ---------------------------------------------------------------------------
// Fused kernel, r27 = r23 verbatim (champion-tied: 39.48-39.68 us fused on
// the fast-toolchain containers, Round 6). r18 structure (32-pt/256-thr,
// 38.9KB LDS, 4 blocks/CU — reg cap 64 VGPR + 64 AGPR = 128/thread and LDS
// cap coincide) plus two schedule-robustness mechanisms, both measured
// neutral-or-better:
//  (1) hidden-layer epilogue VALU BEFORE barrier-1 (packed into uint2 regs);
//      bar1->bar2 segment is just the 16 ds_write_b64.
//  (2) s_setprio(1) around MFMA K-loops.
// Session evidence (r19-r26): tile-aspect rebalance, barrier-free 1-wave,
// merged-bdy 9th tile, LDS-diet occupancy all measured negative; r18/r23
// is the balanced multi-pipe operating point.
// ---------------------------------------------------------------------------
__global__ __launch_bounds__(256, 4) void fused_kernel(
    const float* __restrict__ xt,
    const float* __restrict__ x_inlet, const float* __restrict__ U_inlet,
    const float* __restrict__ x_base,  const float* __restrict__ x_top,
    const float* __restrict__ x_slip,
    const float* __restrict__ W0, const float* __restrict__ b0,
    const float* __restrict__ W1, const float* __restrict__ b1,
    const float* __restrict__ W2, const float* __restrict__ b2,
    const float* __restrict__ W3, const float* __restrict__ b3,
    const float* __restrict__ W4, const float* __restrict__ b4,
    const float* __restrict__ V0, const float* __restrict__ c0,
    const float* __restrict__ V1, const float* __restrict__ c1,
    const float* __restrict__ V2, const float* __restrict__ c2,
    const unsigned short* __restrict__ wsU,
    float* __restrict__ out)
{
    __shared__ float SM[9664];   // 38,656 B
    const int t = threadIdx.x;
    const int wv   = t >> 6;
    const int lane = t & 63;
    const int nn   = lane & 15;
    const int q    = lane >> 4;

    if (blockIdx.x < PHYS_BLOCKS) {
        // =================== PHYSICS PATH (32 pts) ===================
        unsigned short* AhU = (unsigned short*)SM;   // 128 rows x 136 ushorts
        float* OUTF   = SM + 8704;   // 128 x 4
        float* MUPART = SM + 9216;   // 64
        float* BIASF  = SM + 9280;   // 384 floats

        const int blk = blockIdx.x;

        if (t < 128) {
            BIASF[t]       = b1[t];
            BIASF[128 + t] = b2[t];
            BIASF[256 + t] = b3[t];
        }

        // ---- mu net: wave wv -> point-group g = wv>>1, unit-half h = wv&1 --
        {
            const int g = wv >> 1, h = wv & 1;
            const float2 xyn = *(const float2*)(xt + (blk * 32 + g * 16 + nn) * 2);
            FragU mb[2];
            #pragma unroll
            for (int ks = 0; ks < 2; ks++) {
                int u0 = ks * 32 + q * 8;
                F4 va0, va1, vb0, vb1, cc0, cc1;
                va0.v = *(const float4*)(V0 + u0);
                va1.v = *(const float4*)(V0 + u0 + 4);
                vb0.v = *(const float4*)(V0 + 64 + u0);
                vb1.v = *(const float4*)(V0 + 64 + u0 + 4);
                cc0.v = *(const float4*)(c0 + u0);
                cc1.v = *(const float4*)(c0 + u0 + 4);
                #pragma unroll
                for (int i = 0; i < 4; i++) {
                    mb[ks].e[i]     = (_Float16)fast_tanh(
                        xyn.x * va0.f[i] + xyn.y * vb0.f[i] + cc0.f[i]);
                    mb[ks].e[4 + i] = (_Float16)fast_tanh(
                        xyn.x * va1.f[i] + xyn.y * vb1.f[i] + cc1.f[i]);
                }
            }
            float partial = 0.f;
            #pragma unroll
            for (int i = 0; i < 2; i++) {
                f32x4 macc = {0.f, 0.f, 0.f, 0.f};
                #pragma unroll
                for (int ks = 0; ks < 2; ks++) {
                    FragU vh;
                    vh.q = *(const uint4*)(wsU + 98304 +
                           ((((2 * h + i) * 2 + ks) * 64 + lane) << 3));
                    macc = __builtin_amdgcn_mfma_f32_16x16x32_f16(vh.b, mb[ks].b, macc, 0, 0, 0);
                }
                int u2 = (2 * h + i) * 16 + q * 4;
                F4 cv, w2;
                cv.v = *(const float4*)(c1 + u2);
                w2.v = *(const float4*)(V2 + u2);
                #pragma unroll
                for (int r = 0; r < 4; r++)
                    partial += fast_tanh(macc[r] + cv.f[r]) * w2.f[r];
            }
            partial += __shfl_xor(partial, 16);
            partial += __shfl_xor(partial, 32);
            if (lane < 16) MUPART[wv * 16 + nn] = partial;
        }
        {   // main layer 0: 2 -> 128, 4 streams, 2 point-halves per thread
            const int pl = t >> 4, c = t & 15;
            #pragma unroll
            for (int h2 = 0; h2 < 2; h2++) {
                const int p = h2 * 16 + pl;
                const float2 xy = *(const float2*)(xt + (blk * 32 + p) * 2);
                const float x = xy.x, y = xy.y;
                float vals[4][8];
                #pragma unroll
                for (int j = 0; j < 8; j++) {
                    int u = c * 8 + j;
                    float w0 = W0[u], w1 = W0[128 + u];
                    float zv = x * w0 + y * w1 + b0[u];
                    float tt = fast_tanh(zv);
                    float s2 = 1.f - tt * tt;
                    float m2 = -2.f * tt * s2;
                    vals[0][j] = tt;
                    vals[1][j] = s2 * w0;
                    vals[2][j] = s2 * w1;
                    vals[3][j] = m2 * (w0 * w0 + w1 * w1);  // z_lap = 0 at layer 0
                }
                #pragma unroll
                for (int s = 0; s < 4; s++) {
                    uint4 d = make_uint4(pk2(vals[s][0], vals[s][1]),
                                         pk2(vals[s][2], vals[s][3]),
                                         pk2(vals[s][4], vals[s][5]),
                                         pk2(vals[s][6], vals[s][7]));
                    *(uint4*)(AhU + ((h2 * 4 + s) * 16 + pl) * 136 + c * 8) = d;
                }
            }
        }
        __syncthreads();

        // ------- hidden layers 1..3 via MFMA (8 row-tiles, W-hi 1-pass) ----
        #pragma unroll 1
        for (int l = 0; l < 3; l++) {
            const unsigned short* WpL = wsU + l * 32768;
            f32x4 acc[2][8];
            #pragma unroll
            for (int i = 0; i < 2; i++)
                #pragma unroll
                for (int s = 0; s < 8; s++) {
                    acc[i][s][0] = 0.f; acc[i][s][1] = 0.f;
                    acc[i][s][2] = 0.f; acc[i][s][3] = 0.f;
                }
            __builtin_amdgcn_s_setprio(1);
            #pragma unroll
            for (int ks = 0; ks < 4; ks++) {
                FragU wh[2];
                #pragma unroll
                for (int i = 0; i < 2; i++)
                    wh[i].q = *(const uint4*)(WpL + ((((2 * wv + i) * 4 + ks) * 64 + lane) << 3));
                #pragma unroll
                for (int s = 0; s < 8; s++) {
                    FragU bh;
                    bh.q = *(const uint4*)(AhU + (s * 16 + nn) * 136 + ks * 32 + q * 8);
                    acc[0][s] = __builtin_amdgcn_mfma_f32_16x16x32_f16(
                        wh[0].b, bh.b, acc[0][s], 0, 0, 0);
                    acc[1][s] = __builtin_amdgcn_mfma_f32_16x16x32_f16(
                        wh[1].b, bh.b, acc[1][s], 0, 0, 0);
                }
            }
            __builtin_amdgcn_s_setprio(0);
            // ---- epilogue VALU BEFORE barrier (registers only) ----
            uint2 pk[2][2][4];
            #pragma unroll
            for (int i = 0; i < 2; i++) {
                const int ubase = (2 * wv + i) * 16 + q * 4;
                F4 bv; bv.v = *(const float4*)&BIASF[l * 128 + ubase];
                #pragma unroll
                for (int g = 0; g < 2; g++) {
                    float vals[4][4];
                    #pragma unroll
                    for (int r = 0; r < 4; r++) {
                        float z  = acc[i][g * 4 + 0][r] + bv.f[r];
                        float zx = acc[i][g * 4 + 1][r];
                        float zy = acc[i][g * 4 + 2][r];
                        float zl = acc[i][g * 4 + 3][r];
                        float tt = fast_tanh(z);
                        float s2 = 1.f - tt * tt;
                        float m2 = -2.f * tt * s2;
                        vals[0][r] = tt;
                        vals[1][r] = s2 * zx;
                        vals[2][r] = s2 * zy;
                        vals[3][r] = s2 * zl + m2 * (zx * zx + zy * zy);
                    }
                    #pragma unroll
                    for (int s = 0; s < 4; s++)
                        pk[i][g][s] = make_uint2(pk2(vals[s][0], vals[s][1]),
                                                 pk2(vals[s][2], vals[s][3]));
                }
            }
            __syncthreads();   // all A reads done before overwrite
            #pragma unroll
            for (int i = 0; i < 2; i++) {
                const int ubase = (2 * wv + i) * 16 + q * 4;
                #pragma unroll
                for (int g = 0; g < 2; g++)
                    #pragma unroll
                    for (int s = 0; s < 4; s++)
                        *(uint2*)(AhU + ((g * 4 + s) * 16 + nn) * 136 + ubase) = pk[i][g][s];
            }
            __syncthreads();
        }

        // ---------------- layer 4: 128 -> 4 via MFMA (padded W4, hi+lo) ----
        {
            const unsigned short* W4p = wsU + 102400;
            const int rtA = wv, rtB = 4 + wv;
            f32x4 aA = {0.f, 0.f, 0.f, 0.f};
            f32x4 aB = {0.f, 0.f, 0.f, 0.f};
            __builtin_amdgcn_s_setprio(1);
            #pragma unroll
            for (int ks = 0; ks < 4; ks++) {
                FragU wh, wl, bA, bB;
                const unsigned short* base = W4p + ((ks * 64 + lane) << 3);
                wh.q = *(const uint4*)base;
                wl.q = *(const uint4*)(base + 2048);
                bA.q = *(const uint4*)(AhU + (rtA * 16 + nn) * 136 + ks * 32 + q * 8);
                bB.q = *(const uint4*)(AhU + (rtB * 16 + nn) * 136 + ks * 32 + q * 8);
                aA = __builtin_amdgcn_mfma_f32_16x16x32_f16(wh.b, bA.b, aA, 0, 0, 0);
                aA = __builtin_amdgcn_mfma_f32_16x16x32_f16(wl.b, bA.b, aA, 0, 0, 0);
                aB = __builtin_amdgcn_mfma_f32_16x16x32_f16(wh.b, bB.b, aB, 0, 0, 0);
                aB = __builtin_amdgcn_mfma_f32_16x16x32_f16(wl.b, bB.b, aB, 0, 0, 0);
            }
            __builtin_amdgcn_s_setprio(0);
            if (q == 0) {
                float4 oA = make_float4(aA[0], aA[1], aA[2], aA[3]);
                float4 oB = make_float4(aB[0], aB[1], aB[2], aB[3]);
                if (wv == 0) {   // rtA==0 / rtB==4 are the value streams
                    oA.x += b4[0]; oA.y += b4[1]; oA.z += b4[2]; oA.w += b4[3];
                    oB.x += b4[0]; oB.y += b4[1]; oB.z += b4[2]; oB.w += b4[3];
                }
                *(float4*)&OUTF[(rtA * 16 + nn) * 4] = oA;
                *(float4*)&OUTF[(rtB * 16 + nn) * 4] = oB;
            }
        }
        __syncthreads();

        // ---------------- per-point residual + reduction -------------------
        float contrib = 0.f;
        if (t < 32) {
            const int pp = t, g = pp >> 4, p15 = pp & 15;
            const float* V   = &OUTF[((g * 4 + 0) * 16 + p15) * 4];
            const float* DX  = &OUTF[((g * 4 + 1) * 16 + p15) * 4];
            const float* DY  = &OUTF[((g * 4 + 2) * 16 + p15) * 4];
            const float* LAP = &OUTF[((g * 4 + 3) * 16 + p15) * 4];
            float r = V[0],  P = V[1],  u = V[2],  v = V[3];
            float rx = DX[0], Px = DX[1], ux = DX[2], vx = DX[3];
            float ry = DY[0], Py = DY[1], uy = DY[2], vy = DY[3];
            float rl = LAP[0], Pl = LAP[1], ul = LAP[2], vl = LAP[3];
            const float GI = 2.5f;  // 1/(gamma-1)

            float s = MUPART[(2 * g) * 16 + p15] + MUPART[(2 * g + 1) * 16 + p15]
                    + c2[0];
            float mu = 0.01f * s * s;

            float q2 = u * u + v * v;
            float E  = P * GI + 0.5f * r * q2;
            float Ex = Px * GI + 0.5f * rx * q2 + r * (u * ux + v * vx);
            float Ey = Py * GI + 0.5f * ry * q2 + r * (u * uy + v * vy);
            float EpP = E + P;

            float f1x = rx * u + r * ux;
            float f2x = rx * u * u + 2.f * r * u * ux + Px;
            float f3x = rx * u * v + r * ux * v + r * u * vx;
            float f4x = ux * EpP + u * (Ex + Px);

            float g1y = ry * v + r * vy;
            float g2y = ry * u * v + r * uy * v + r * u * vy;
            float g3y = ry * v * v + 2.f * r * v * vy + Py;
            float g4y = vy * EpP + v * (Ey + Py);

            float qx  = 2.f * (u * ux + v * vx);
            float qy  = 2.f * (u * uy + v * vy);
            float ql  = 2.f * (ux * ux + uy * uy + vx * vx + vy * vy)
                      + 2.f * (u * ul + v * vl);

            float U1s = rl;
            float U2s = rl * u + 2.f * (rx * ux + ry * uy) + r * ul;
            float U3s = rl * v + 2.f * (rx * vx + ry * vy) + r * vl;
            float U4s = Pl * GI
                      + 0.5f * (rl * q2 + 2.f * (rx * qx + ry * qy) + r * ql);

            float r1 = f1x + g1y - mu * U1s;
            float r2 = f2x + g2y - mu * U2s;
            float r3 = f3x + g3y - mu * U3s;
            float r4 = f4x + g4y - mu * U4s;

            contrib = (r1 * r1 + r2 * r2 + r3 * r3 + r4 * r4 + 0.1f * mu * mu)
                      * (1.0f / (float)NTRAIN);
        }
        if (t < 64) {
            contrib += __shfl_down(contrib, 32);
            contrib += __shfl_down(contrib, 16);
            contrib += __shfl_down(contrib, 8);
            contrib += __shfl_down(contrib, 4);
            contrib += __shfl_down(contrib, 2);
            contrib += __shfl_down(contrib, 1);
            if (t == 0) atomicAdd(out, contrib);
        }
    } else {
        // =================== BOUNDARY PATH (MFMA, 64 pts/block) ============
        unsigned short* ShU = (unsigned short*)SM;   // 64 x 136
        float* OUTB  = SM + 4352;   // 64 x 4
        float* BIASB = SM + 4608;   // 384 floats

        const int bb    = blockIdx.x - PHYS_BLOCKS;
        const int batch = bb >> 6;  // 0..3 (64 blocks each)
        const int lb    = bb & 63;
        const float* xs = (batch == 0) ? x_inlet
                        : (batch == 1) ? x_base
                        : (batch == 2) ? x_top : x_slip;
        const int base_pt = lb * 64;

        // ---- layer 0: 2 -> 128 (4 threads/pt, 32 units each) + biases ----
        {
            int p2 = t & 63, ug = t >> 6;
            float2 xy = *(const float2*)(xs + (base_pt + p2) * 2);
            float x = xy.x, y = xy.y;
            #pragma unroll
            for (int g = 0; g < 8; g++) {
                int u0 = ug * 32 + g * 4;
                F4 wa, wb, bbv;
                wa.v  = *(const float4*)(W0 + u0);
                wb.v  = *(const float4*)(W0 + 128 + u0);
                bbv.v = *(const float4*)(b0 + u0);
                float t0 = fast_tanh(x * wa.f[0] + y * wb.f[0] + bbv.f[0]);
                float t1 = fast_tanh(x * wa.f[1] + y * wb.f[1] + bbv.f[1]);
                float t2 = fast_tanh(x * wa.f[2] + y * wb.f[2] + bbv.f[2]);
                float t3 = fast_tanh(x * wa.f[3] + y * wb.f[3] + bbv.f[3]);
                uint2 d = make_uint2(pk2(t0, t1), pk2(t2, t3));
                *(uint2*)(ShU + p2 * 136 + u0) = d;
            }
            if (t < 128) {
                BIASB[t]       = b1[t];
                BIASB[128 + t] = b2[t];
                BIASB[256 + t] = b3[t];
            }
        }
        __syncthreads();

        // ---- hidden layers 1..3 via MFMA (W hi only, 4 point-tiles) ----
        #pragma unroll 1
        for (int l = 0; l < 3; l++) {
            const unsigned short* WpL = wsU + l * 32768;
            f32x4 acc[2][4];
            #pragma unroll
            for (int i = 0; i < 2; i++)
                #pragma unroll
                for (int n = 0; n < 4; n++) {
                    acc[i][n][0] = 0.f; acc[i][n][1] = 0.f;
                    acc[i][n][2] = 0.f; acc[i][n][3] = 0.f;
                }
            __builtin_amdgcn_s_setprio(1);
            #pragma unroll
            for (int ks = 0; ks < 4; ks++) {
                FragU bh[4];
                #pragma unroll
                for (int n = 0; n < 4; n++)
                    bh[n].q = *(const uint4*)(ShU + (n * 16 + nn) * 136 + ks * 32 + q * 8);
                FragU wh[2];
                #pragma unroll
                for (int i = 0; i < 2; i++)
                    wh[i].q = *(const uint4*)(WpL + ((((2 * wv + i) * 4 + ks) * 64 + lane) << 3));
                #pragma unroll
                for (int i = 0; i < 2; i++)
                    #pragma unroll
                    for (int n = 0; n < 4; n++)
                        acc[i][n] = __builtin_amdgcn_mfma_f32_16x16x32_f16(
                            wh[i].b, bh[n].b, acc[i][n], 0, 0, 0);
            }
            __builtin_amdgcn_s_setprio(0);
            // ---- epilogue VALU BEFORE barrier (registers only) ----
            uint2 pk[2][4];
            #pragma unroll
            for (int i = 0; i < 2; i++) {
                int ubase = (2 * wv + i) * 16 + q * 4;
                F4 bv; bv.v = *(const float4*)&BIASB[l * 128 + ubase];
                #pragma unroll
                for (int n = 0; n < 4; n++) {
                    float t0 = fast_tanh(acc[i][n][0] + bv.f[0]);
                    float t1 = fast_tanh(acc[i][n][1] + bv.f[1]);
                    float t2 = fast_tanh(acc[i][n][2] + bv.f[2]);
                    float t3 = fast_tanh(acc[i][n][3] + bv.f[3]);
                    pk[i][n] = make_uint2(pk2(t0, t1), pk2(t2, t3));
                }
            }
            __syncthreads();
            #pragma unroll
            for (int i = 0; i < 2; i++) {
                int ubase = (2 * wv + i) * 16 + q * 4;
                #pragma unroll
                for (int n = 0; n < 4; n++)
                    *(uint2*)(ShU + (n * 16 + nn) * 136 + ubase) = pk[i][n];
            }
            __syncthreads();
        }

        // ---- layer 4 via MFMA (padded W4, hi+lo), one point-tile/wave ----
        {
            const unsigned short* W4p = wsU + 102400;
            f32x4 a4 = {0.f, 0.f, 0.f, 0.f};
            __builtin_amdgcn_s_setprio(1);
            #pragma unroll
            for (int ks = 0; ks < 4; ks++) {
                FragU bh, wh, wl;
                bh.q = *(const uint4*)(ShU + (wv * 16 + nn) * 136 + ks * 32 + q * 8);
                const unsigned short* base = W4p + ((ks * 64 + lane) << 3);
                wh.q = *(const uint4*)base;
                wl.q = *(const uint4*)(base + 2048);
                a4 = __builtin_amdgcn_mfma_f32_16x16x32_f16(wh.b, bh.b, a4, 0, 0, 0);
                a4 = __builtin_amdgcn_mfma_f32_16x16x32_f16(wl.b, bh.b, a4, 0, 0, 0);
            }
            __builtin_amdgcn_s_setprio(0);
            if (q == 0) {
                float4 o = make_float4(a4[0] + b4[0], a4[1] + b4[1],
                                       a4[2] + b4[2], a4[3] + b4[3]);
                *(float4*)&OUTB[(wv * 16 + nn) * 4] = o;
            }
        }
        __syncthreads();

        float contrib = 0.f;
        if (t < 64) {
            float o0 = OUTB[t * 4 + 0], o1 = OUTB[t * 4 + 1];
            float o2 = OUTB[t * 4 + 2], o3 = OUTB[t * 4 + 3];
            float l;
            if (batch == 0) {
                float4 Ui = *(const float4*)(U_inlet + (base_pt + t) * 4);
                float d0 = o0 - Ui.x, d1 = o1 - Ui.y, d2 = o2 - Ui.z, d3 = o3 - Ui.w;
                l = d0 * d0 + d1 * d1 + d2 * d2 + d3 * d3;
            } else if (batch == 3) {
                const float sa = -0.17364817766693033f;  // sin(-pi/18)
                const float ca =  0.9848077530122080f;   // cos(-pi/18)
                float d = -o2 * sa + o3 * ca;
                l = d * d;
            } else {
                l = o3 * o3;
            }
            contrib = 10.0f * l * (1.0f / (float)NBDY);
        }
        if (t < 64) {
            contrib += __shfl_down(contrib, 32);
            contrib += __shfl_down(contrib, 16);
            contrib += __shfl_down(contrib, 8);
            contrib += __shfl_down(contrib, 4);
            contrib += __shfl_down(contrib, 2);
            contrib += __shfl_down(contrib, 1);
            if (t == 0) atomicAdd(out, contrib);
        }
    }
}

extern "C" void kernel_launch(void* const* d_in, const int* in_sizes, int n_in,
                              void* d_out, int out_size, void* d_ws, size_t ws_size,
                              hipStream_t stream) {
    const float* xt      = (const float*)d_in[0];
    const float* x_inlet = (const float*)d_in[1];
    const float* U_inlet = (const float*)d_in[2];
    const float* x_base  = (const float*)d_in[3];
    const float* x_top   = (const float*)d_in[4];
    const float* x_slip  = (const float*)d_in[5];
    const float* W0 = (const float*)d_in[6];
    const float* b0 = (const float*)d_in[7];
    const float* W1 = (const float*)d_in[8];
    const float* b1 = (const float*)d_in[9];
    const float* W2 = (const float*)d_in[10];
    const float* b2 = (const float*)d_in[11];
    const float* W3 = (const float*)d_in[12];
    const float* b3 = (const float*)d_in[13];
    const float* W4 = (const float*)d_in[14];
    const float* b4 = (const float*)d_in[15];
    const float* V0 = (const float*)d_in[16];
    const float* c0 = (const float*)d_in[17];
    const float* V1 = (const float*)d_in[18];
    const float* c1 = (const float*)d_in[19];
    const float* V2 = (const float*)d_in[20];
    const float* c2 = (const float*)d_in[21];
    float* out = (float*)d_out;
    unsigned short* wsU = (unsigned short*)d_ws;

    pack_w_kernel<<<26, 256, 0, stream>>>(W1, W2, W3, V1, W4, wsU, out);

    fused_kernel<<<PHYS_BLOCKS + BDY_BLOCKS, 256, 0, stream>>>(
        xt, x_inlet, U_inlet, x_base, x_top, x_slip,
        W0, b0, W1, b1, W2, b2, W3, b3, W4, b4,
        V0, c0, V1, c1, V2, c2, wsU, out);
}